// Round 1
// baseline (8802.872 us; speedup 1.0000x reference)
//
#include <hip/hip_runtime.h>
#include <math.h>

// Performer encoder: B=4, S=4096, D=256, H=4, DH=64, L=4, M=266. All fp32.

#define WS_ALIGN(x) (((x) + 255) & ~(size_t)255)

#define DN 0.35355339059327373f      // 64^-0.25
#define DIAGC 0.0625f                 // 0.5 * 64^-0.5
#define RATIO 0.06131393394849658f    // 266^-0.5
#define FEPS 1e-4f

__device__ __forceinline__ float wredsum(float v) {
    v += __shfl_xor(v, 32); v += __shfl_xor(v, 16); v += __shfl_xor(v, 8);
    v += __shfl_xor(v, 4);  v += __shfl_xor(v, 2);  v += __shfl_xor(v, 1);
    return v;
}
__device__ __forceinline__ float wredmax(float v) {
    v = fmaxf(v, __shfl_xor(v, 32)); v = fmaxf(v, __shfl_xor(v, 16));
    v = fmaxf(v, __shfl_xor(v, 8));  v = fmaxf(v, __shfl_xor(v, 4));
    v = fmaxf(v, __shfl_xor(v, 2));  v = fmaxf(v, __shfl_xor(v, 1));
    return v;
}

// x = LN(in (+ pos)) * g + b   — one block per row of 256
__global__ __launch_bounds__(256) void add_ln_kernel(
    const float* __restrict__ in, const float* __restrict__ pos,
    const float* __restrict__ g, const float* __restrict__ bta,
    float* __restrict__ out)
{
    int row = blockIdx.x, t = threadIdx.x;
    __shared__ float sred[4];
    float v = in[(size_t)row * 256 + t];
    if (pos) v += pos[(size_t)(row & 4095) * 256 + t];
    float s = wredsum(v);
    if ((t & 63) == 0) sred[t >> 6] = s;
    __syncthreads();
    float mean = (sred[0] + sred[1] + sred[2] + sred[3]) * (1.0f / 256.0f);
    float d = v - mean;
    __syncthreads();
    float sq = wredsum(d * d);
    if ((t & 63) == 0) sred[t >> 6] = sq;
    __syncthreads();
    float var = (sred[0] + sred[1] + sred[2] + sred[3]) * (1.0f / 256.0f);
    out[(size_t)row * 256 + t] = d * rsqrtf(var + 1e-12f) * g[t] + bta[t];
}

// C[M,N] = act(A[M,K] @ W[K,N] + bias) (+ resid). ACT: 0 none, 1 gelu(tanh), 2 tanh
template <int ACT>
__global__ __launch_bounds__(256) void gemm_kernel(
    const float* __restrict__ A, const float* __restrict__ W,
    const float* __restrict__ bias, const float* __restrict__ resid,
    float* __restrict__ C, int M, int N, int K)
{
    __shared__ float As[16][64];
    __shared__ float Bs[16][64];
    int t = threadIdx.x;
    int bm = blockIdx.y * 64, bn = blockIdx.x * 64;
    int tx = t & 15, ty = t >> 4;
    int arow = t >> 2, acol = (t & 3) << 2;
    int brow = t >> 4, bcol = (t & 15) << 2;
    float acc[4][4] = {};
    for (int k0 = 0; k0 < K; k0 += 16) {
        float4 av = *(const float4*)(A + (size_t)(bm + arow) * K + k0 + acol);
        As[acol + 0][arow] = av.x; As[acol + 1][arow] = av.y;
        As[acol + 2][arow] = av.z; As[acol + 3][arow] = av.w;
        *(float4*)(&Bs[brow][bcol]) = *(const float4*)(W + (size_t)(k0 + brow) * N + bn + bcol);
        __syncthreads();
#pragma unroll
        for (int k = 0; k < 16; k++) {
            float4 a4 = *(const float4*)(&As[k][ty << 2]);
            float4 b4 = *(const float4*)(&Bs[k][tx << 2]);
            acc[0][0] += a4.x * b4.x; acc[0][1] += a4.x * b4.y; acc[0][2] += a4.x * b4.z; acc[0][3] += a4.x * b4.w;
            acc[1][0] += a4.y * b4.x; acc[1][1] += a4.y * b4.y; acc[1][2] += a4.y * b4.z; acc[1][3] += a4.y * b4.w;
            acc[2][0] += a4.z * b4.x; acc[2][1] += a4.z * b4.y; acc[2][2] += a4.z * b4.z; acc[2][3] += a4.z * b4.w;
            acc[3][0] += a4.w * b4.x; acc[3][1] += a4.w * b4.y; acc[3][2] += a4.w * b4.z; acc[3][3] += a4.w * b4.w;
        }
        __syncthreads();
    }
#pragma unroll
    for (int i = 0; i < 4; i++) {
        int row = bm + (ty << 2) + i;
        int col = bn + (tx << 2);
        float vj[4];
#pragma unroll
        for (int j = 0; j < 4; j++) {
            float v = acc[i][j] + bias[col + j];
            if (ACT == 1) {
                float inner = 0.7978845608028654f * (v + 0.044715f * v * v * v);
                v = 0.5f * v * (1.0f + tanhf(inner));
            } else if (ACT == 2) {
                v = tanhf(v);
            }
            if (resid) v += resid[(size_t)row * N + col + j];
            vj[j] = v;
        }
        float4 r = make_float4(vj[0], vj[1], vj[2], vj[3]);
        *(float4*)(C + (size_t)row * N + col) = r;
    }
}

__device__ __forceinline__ float dot64(const float* qs, const float* __restrict__ pr) {
    const float4* q4 = (const float4*)qs;
    const float4* p4 = (const float4*)pr;
    float s = 0.f;
#pragma unroll
    for (int i = 0; i < 16; i++) {
        float4 a = q4[i], b = p4[i];
        s += a.x * b.x + a.y * b.y + a.z * b.z + a.w * b.w;
    }
    return s;
}

// qp[r,m] = ratio*(exp(dash - diag - rowmax) + eps), one block per (b,h,s)
__global__ __launch_bounds__(256) void phi_q_kernel(
    const float* __restrict__ q, const float* __restrict__ proj, float* __restrict__ qp)
{
    __shared__ __align__(16) float qs[64];
    __shared__ float sred[8];
    int r = blockIdx.x, t = threadIdx.x;
    int b = r >> 14, h = (r >> 12) & 3, s = r & 4095;
    const float* qrow = q + ((size_t)((b << 12) + s) << 8) + (h << 6);
    if (t < 64) qs[t] = qrow[t];
    __syncthreads();
    float p = (t < 64) ? qs[t] * qs[t] : 0.f;
    p = wredsum(p);
    if ((t & 63) == 0) sred[t >> 6] = p;
    __syncthreads();
    float diag = DIAGC * (sred[0] + sred[1] + sred[2] + sred[3]);
    float d0 = dot64(qs, proj + ((size_t)t << 6)) * DN;
    bool has1 = (t < 10);
    float d1 = has1 ? dot64(qs, proj + ((size_t)(t + 256) << 6)) * DN : -1e30f;
    float lm = fmaxf(d0, d1);
    lm = wredmax(lm);
    if ((t & 63) == 0) sred[4 + (t >> 6)] = lm;
    __syncthreads();
    float stab = fmaxf(fmaxf(sred[4], sred[5]), fmaxf(sred[6], sred[7]));
    size_t base = (size_t)r * 266;
    qp[base + t] = RATIO * (expf(d0 - diag - stab) + FEPS);
    if (has1) qp[base + t + 256] = RATIO * (expf(d1 - diag - stab) + FEPS);
}

// keys pass1: raw dash + diag + per-block max
__global__ __launch_bounds__(256) void phi_k1_kernel(
    const float* __restrict__ kq, const float* __restrict__ proj,
    float* __restrict__ dash, float* __restrict__ diagb, float* __restrict__ pmax)
{
    __shared__ __align__(16) float qs[64];
    __shared__ float sred[8];
    int r = blockIdx.x, t = threadIdx.x;
    int b = r >> 14, h = (r >> 12) & 3, s = r & 4095;
    const float* krow = kq + ((size_t)((b << 12) + s) << 8) + (h << 6);
    if (t < 64) qs[t] = krow[t];
    __syncthreads();
    float p = (t < 64) ? qs[t] * qs[t] : 0.f;
    p = wredsum(p);
    if ((t & 63) == 0) sred[t >> 6] = p;
    __syncthreads();
    float diag = DIAGC * (sred[0] + sred[1] + sred[2] + sred[3]);
    float d0 = dot64(qs, proj + ((size_t)t << 6)) * DN;
    bool has1 = (t < 10);
    float d1 = has1 ? dot64(qs, proj + ((size_t)(t + 256) << 6)) * DN : -1e30f;
    size_t base = (size_t)r * 266;
    dash[base + t] = d0;
    if (has1) dash[base + t + 256] = d1;
    float lm = fmaxf(d0, d1);
    lm = wredmax(lm);
    if ((t & 63) == 0) sred[4 + (t >> 6)] = lm;
    __syncthreads();
    if (t == 0) {
        diagb[r] = diag;
        pmax[blockIdx.x] = fmaxf(fmaxf(sred[4], sred[5]), fmaxf(sred[6], sred[7]));
    }
}

__global__ __launch_bounds__(256) void reduce_max_kernel(
    const float* __restrict__ pmax, float* __restrict__ stab, int n)
{
    __shared__ float sred[4];
    int t = threadIdx.x;
    float m = -1e30f;
    for (int i = t; i < n; i += 256) m = fmaxf(m, pmax[i]);
    m = wredmax(m);
    if ((t & 63) == 0) sred[t >> 6] = m;
    __syncthreads();
    if (t == 0) stab[0] = fmaxf(fmaxf(sred[0], sred[1]), fmaxf(sred[2], sred[3]));
}

__global__ __launch_bounds__(256) void phi_k2_kernel(
    float* __restrict__ dash, const float* __restrict__ diagb,
    const float* __restrict__ stab, int total)
{
    int i = blockIdx.x * 256 + threadIdx.x;
    if (i >= total) return;
    int r = i / 266;
    float st = stab[0];
    dash[i] = RATIO * (expf(dash[i] - diagb[r] - st) + FEPS);
}

// ksum[bh,m] = sum_s kp[bh,s,m]  (s split across blockIdx.z, atomic combine)
__global__ __launch_bounds__(256) void ksum_kernel(
    const float* __restrict__ kp, float* __restrict__ ksum)
{
    int m = blockIdx.x * 256 + threadIdx.x;
    if (m >= 266) return;
    int bh = blockIdx.y;
    int s0 = blockIdx.z * 256;
    float s = 0.f;
    size_t base = ((size_t)(bh << 12) + s0) * 266 + m;
    for (int i = 0; i < 256; i++) s += kp[base + (size_t)i * 266];
    atomicAdd(&ksum[bh * 266 + m], s);
}

// ctx[bh,m,e] += sum_s kp[bh,s,m] * v[b,s,h*64+e]
__global__ __launch_bounds__(256) void ctx_kernel(
    const float* __restrict__ kp, const float* __restrict__ v, float* __restrict__ ctx)
{
    __shared__ float ks[32][32];
    __shared__ float vs[32][64];
    int t = threadIdx.x;
    int m0 = blockIdx.x * 32;
    int bh = blockIdx.y;
    int b = bh >> 2, h = bh & 3;
    int s0 = blockIdx.z * 512;
    int e = t & 63, mg = t >> 6;
    float acc[8] = {};
    int ml = t & 31, sl = t >> 5;
    for (int st = 0; st < 512; st += 32) {
#pragma unroll
        for (int p = 0; p < 4; p++) {
            int ss = sl + p * 8;
            int m = m0 + ml;
            ks[ss][ml] = (m < 266) ? kp[((size_t)(bh << 12) + s0 + st + ss) * 266 + m] : 0.f;
        }
#pragma unroll
        for (int p = 0; p < 8; p++) {
            int ss = (t >> 6) + p * 4;
            vs[ss][e] = v[((size_t)(b << 12) + s0 + st + ss) * 256 + (h << 6) + e];
        }
        __syncthreads();
#pragma unroll
        for (int ss = 0; ss < 32; ss++) {
            float vv = vs[ss][e];
#pragma unroll
            for (int j = 0; j < 8; j++) acc[j] += ks[ss][mg * 8 + j] * vv;
        }
        __syncthreads();
    }
#pragma unroll
    for (int j = 0; j < 8; j++) {
        int m = m0 + mg * 8 + j;
        if (m < 266) atomicAdd(&ctx[((size_t)bh * 266 + m) * 64 + e], acc[j]);
    }
}

// per (b,h,s): denom = qp·ksum ; out[e] = (qp·ctx[:,e]) / denom
__global__ __launch_bounds__(256) void attnout_kernel(
    const float* __restrict__ qp, const float* __restrict__ ksum,
    const float* __restrict__ ctx, float* __restrict__ ab)
{
    __shared__ float qs[266];
    __shared__ float sred[4];
    __shared__ float red2[4][64];
    int r = blockIdx.x, t = threadIdx.x;
    int bh = r >> 12;
    int b = bh >> 2, h = bh & 3, s = r & 4095;
    const float* qrow = qp + (size_t)r * 266;
    qs[t] = qrow[t];
    if (t < 10) qs[256 + t] = qrow[256 + t];
    __syncthreads();
    float p = qs[t] * ksum[bh * 266 + t];
    if (t < 10) p += qs[256 + t] * ksum[bh * 266 + 256 + t];
    p = wredsum(p);
    if ((t & 63) == 0) sred[t >> 6] = p;
    __syncthreads();
    float dinv = 1.0f / (sred[0] + sred[1] + sred[2] + sred[3]);
    int e = t & 63, g = t >> 6;
    float acc = 0.f;
    for (int m = g; m < 266; m += 4) acc += qs[m] * ctx[((size_t)bh * 266 + m) * 64 + e];
    red2[g][e] = acc;
    __syncthreads();
    if (t < 64) {
        float o = (red2[0][t] + red2[1][t] + red2[2][t] + red2[3][t]) * dinv;
        ab[((size_t)(b << 12) + s) * 256 + (h << 6) + t] = o;
    }
}

// alpha[row] = exp(e_row · p2w + p2b) * mask[row]
__global__ __launch_bounds__(256) void pool_score_kernel(
    const float* __restrict__ e, const float* __restrict__ p2w,
    const float* __restrict__ p2b, const float* __restrict__ mask, float* __restrict__ alpha)
{
    __shared__ float sred[4];
    int row = blockIdx.x, t = threadIdx.x;
    float p = e[(size_t)row * 256 + t] * p2w[t];
    p = wredsum(p);
    if ((t & 63) == 0) sred[t >> 6] = p;
    __syncthreads();
    if (t == 0) {
        float sc = sred[0] + sred[1] + sred[2] + sred[3] + p2b[0];
        alpha[row] = expf(sc) * mask[row];
    }
}

__global__ __launch_bounds__(256) void pool_denom_kernel(
    const float* __restrict__ alpha, float* __restrict__ denomb)
{
    __shared__ float sred[4];
    int b = blockIdx.x, t = threadIdx.x;
    float p = 0.f;
    for (int s = t; s < 4096; s += 256) p += alpha[b * 4096 + s];
    p = wredsum(p);
    if ((t & 63) == 0) sred[t >> 6] = p;
    __syncthreads();
    if (t == 0) denomb[b] = sred[0] + sred[1] + sred[2] + sred[3] + 1e-8f;
}

__global__ __launch_bounds__(256) void pool_out_kernel(
    const float* __restrict__ x, const float* __restrict__ alpha,
    const float* __restrict__ denomb, float* __restrict__ out)
{
    int b = blockIdx.x, chunk = blockIdx.y, t = threadIdx.x;
    float inv = 1.0f / denomb[b];
    float acc = 0.f;
    int s0 = chunk * 128;
    for (int s = s0; s < s0 + 128; s++)
        acc += x[((size_t)(b << 12) + s) * 256 + t] * alpha[(b << 12) + s];
    atomicAdd(&out[b * 256 + t], acc * inv);
}

extern "C" void kernel_launch(void* const* d_in, const int* in_sizes, int n_in,
                              void* d_out, int out_size, void* d_ws, size_t ws_size,
                              hipStream_t stream)
{
    const float* input_embs = (const float*)d_in[0];
    const float* mask  = (const float*)d_in[1];
    const float* pos   = (const float*)d_in[2];
    const float* ln_g  = (const float*)d_in[3];
    const float* ln_b  = (const float*)d_in[4];
    const float* proj  = (const float*)d_in[5];
    const float* Wq = (const float*)d_in[6];  const float* bq = (const float*)d_in[7];
    const float* Wk = (const float*)d_in[8];  const float* bk = (const float*)d_in[9];
    const float* Wv = (const float*)d_in[10]; const float* bv = (const float*)d_in[11];
    const float* Wo = (const float*)d_in[12]; const float* bo = (const float*)d_in[13];
    const float* ln1g = (const float*)d_in[14]; const float* ln1b = (const float*)d_in[15];
    const float* W1 = (const float*)d_in[16]; const float* b1 = (const float*)d_in[17];
    const float* W2 = (const float*)d_in[18]; const float* b2 = (const float*)d_in[19];
    const float* ln2g = (const float*)d_in[20]; const float* ln2b = (const float*)d_in[21];
    const float* p1w = (const float*)d_in[22]; const float* p1b = (const float*)d_in[23];
    const float* p2w = (const float*)d_in[24]; const float* p2b = (const float*)d_in[25];
    float* out = (float*)d_out;
    char* ws = (char*)d_ws;

    size_t off = 0;
    auto alloc = [&](size_t bytes) { size_t o = off; off += WS_ALIGN(bytes); return o; };
    float* xbuf  = (float*)(ws + alloc(16384ull * 256 * 4));
    float* hbuf  = (float*)(ws + alloc(16384ull * 256 * 4));
    float* qbuf  = (float*)(ws + alloc(16384ull * 256 * 4));
    float* kbuf  = (float*)(ws + alloc(16384ull * 256 * 4));
    float* vbuf  = (float*)(ws + alloc(16384ull * 256 * 4));
    size_t qp_bytes = 4ull * 4 * 4096 * 266 * 4;         // 69,730,304 B
    float* qpbuf = (float*)(ws + alloc(qp_bytes));        // also FFN mid (needs 67,108,864 B)
    float* kpbuf = (float*)(ws + alloc(qp_bytes));
    float* diagb = (float*)(ws + alloc(65536ull * 4));
    float* pmaxb = (float*)(ws + alloc(65536ull * 4));
    float* stabb = (float*)(ws + alloc(256));
    size_t ksum_off = alloc(16ull * 266 * 4);
    float* ksumb = (float*)(ws + ksum_off);
    size_t ctx_off = alloc(16ull * 266 * 64 * 4);
    float* ctxb = (float*)(ws + ctx_off);
    float* alphab = (float*)(ws + alloc(16384ull * 4));
    float* denomb = (float*)(ws + alloc(256));
    float* midbuf = qpbuf;
    size_t ksum_ctx_bytes = (ctx_off + WS_ALIGN(16ull * 266 * 64 * 4)) - ksum_off;

    // x = LN(input + pos)
    add_ln_kernel<<<16384, 256, 0, stream>>>(input_embs, pos, ln_g, ln_b, xbuf);

    for (int i = 0; i < 4; i++) {
        const float* pj = proj + (size_t)i * 266 * 64;
        add_ln_kernel<<<16384, 256, 0, stream>>>(xbuf, nullptr, ln1g + i * 256, ln1b + i * 256, hbuf);
        gemm_kernel<0><<<dim3(4, 256), 256, 0, stream>>>(hbuf, Wq + (size_t)i * 65536, bq + i * 256, nullptr, qbuf, 16384, 256, 256);
        gemm_kernel<0><<<dim3(4, 256), 256, 0, stream>>>(hbuf, Wk + (size_t)i * 65536, bk + i * 256, nullptr, kbuf, 16384, 256, 256);
        gemm_kernel<0><<<dim3(4, 256), 256, 0, stream>>>(hbuf, Wv + (size_t)i * 65536, bv + i * 256, nullptr, vbuf, 16384, 256, 256);
        phi_q_kernel<<<65536, 256, 0, stream>>>(qbuf, pj, qpbuf);
        phi_k1_kernel<<<65536, 256, 0, stream>>>(kbuf, pj, kpbuf, diagb, pmaxb);
        reduce_max_kernel<<<1, 256, 0, stream>>>(pmaxb, stabb, 65536);
        phi_k2_kernel<<<(4 * 4 * 4096 * 266 + 255) / 256, 256, 0, stream>>>(kpbuf, diagb, stabb, 4 * 4 * 4096 * 266);
        hipMemsetAsync(ws + ksum_off, 0, ksum_ctx_bytes, stream);
        ksum_kernel<<<dim3(2, 16, 16), 256, 0, stream>>>(kpbuf, ksumb);
        ctx_kernel<<<dim3(9, 16, 8), 256, 0, stream>>>(kpbuf, vbuf, ctxb);
        attnout_kernel<<<65536, 256, 0, stream>>>(qpbuf, ksumb, ctxb, hbuf);
        gemm_kernel<0><<<dim3(4, 256), 256, 0, stream>>>(hbuf, Wo + (size_t)i * 65536, bo + i * 256, xbuf, xbuf, 16384, 256, 256);
        add_ln_kernel<<<16384, 256, 0, stream>>>(xbuf, nullptr, ln2g + i * 256, ln2b + i * 256, hbuf);
        gemm_kernel<1><<<dim3(16, 256), 256, 0, stream>>>(hbuf, W1 + (size_t)i * 262144, b1 + i * 1024, nullptr, midbuf, 16384, 1024, 256);
        gemm_kernel<0><<<dim3(4, 256), 256, 0, stream>>>(midbuf, W2 + (size_t)i * 262144, b2 + i * 256, xbuf, xbuf, 16384, 256, 1024);
    }

    // Attention pooling
    gemm_kernel<2><<<dim3(4, 256), 256, 0, stream>>>(xbuf, p1w, p1b, nullptr, hbuf, 16384, 256, 256);
    pool_score_kernel<<<16384, 256, 0, stream>>>(hbuf, p2w, p2b, mask, alphab);
    pool_denom_kernel<<<4, 256, 0, stream>>>(alphab, denomb);
    hipMemsetAsync(d_out, 0, (size_t)out_size * sizeof(float), stream);
    pool_out_kernel<<<dim3(4, 32), 256, 0, stream>>>(xbuf, alphab, denomb, out);
}

// Round 2
// 8636.501 us; speedup vs baseline: 1.0193x; 1.0193x over previous
//
#include <hip/hip_runtime.h>
#include <math.h>

// Performer encoder: B=4, S=4096, D=256, H=4, DH=64, L=4, M=266. All fp32.

#define WS_ALIGN(x) (((x) + 255) & ~(size_t)255)

#define DN 0.35355339059327373f      // 64^-0.25
#define DIAGC 0.0625f                 // 0.5 * 64^-0.5
#define RATIO 0.06131393394849658f    // 266^-0.5
#define FEPS 1e-4f

__device__ __forceinline__ float wredsum(float v) {
    v += __shfl_xor(v, 32); v += __shfl_xor(v, 16); v += __shfl_xor(v, 8);
    v += __shfl_xor(v, 4);  v += __shfl_xor(v, 2);  v += __shfl_xor(v, 1);
    return v;
}
__device__ __forceinline__ float wredmax(float v) {
    v = fmaxf(v, __shfl_xor(v, 32)); v = fmaxf(v, __shfl_xor(v, 16));
    v = fmaxf(v, __shfl_xor(v, 8));  v = fmaxf(v, __shfl_xor(v, 4));
    v = fmaxf(v, __shfl_xor(v, 2));  v = fmaxf(v, __shfl_xor(v, 1));
    return v;
}

// x = LN(in (+ pos)) * g + b   — one block per row of 256
__global__ __launch_bounds__(256) void add_ln_kernel(
    const float* __restrict__ in, const float* __restrict__ pos,
    const float* __restrict__ g, const float* __restrict__ bta,
    float* __restrict__ out)
{
    int row = blockIdx.x, t = threadIdx.x;
    __shared__ float sred[4];
    float v = in[(size_t)row * 256 + t];
    if (pos) v += pos[(size_t)(row & 4095) * 256 + t];
    float s = wredsum(v);
    if ((t & 63) == 0) sred[t >> 6] = s;
    __syncthreads();
    float mean = (sred[0] + sred[1] + sred[2] + sred[3]) * (1.0f / 256.0f);
    float d = v - mean;
    __syncthreads();
    float sq = wredsum(d * d);
    if ((t & 63) == 0) sred[t >> 6] = sq;
    __syncthreads();
    float var = (sred[0] + sred[1] + sred[2] + sred[3]) * (1.0f / 256.0f);
    out[(size_t)row * 256 + t] = d * rsqrtf(var + 1e-12f) * g[t] + bta[t];
}

// C[M,N] = act(A[M,K] @ W[K,N] + bias) (+ resid). ACT: 0 none, 1 gelu(tanh), 2 tanh
template <int ACT>
__global__ __launch_bounds__(256) void gemm_kernel(
    const float* __restrict__ A, const float* __restrict__ W,
    const float* __restrict__ bias, const float* __restrict__ resid,
    float* __restrict__ C, int M, int N, int K)
{
    __shared__ float As[16][64];
    __shared__ float Bs[16][64];
    int t = threadIdx.x;
    int bm = blockIdx.y * 64, bn = blockIdx.x * 64;
    int tx = t & 15, ty = t >> 4;
    int arow = t >> 2, acol = (t & 3) << 2;
    int brow = t >> 4, bcol = (t & 15) << 2;
    float acc[4][4] = {};
    for (int k0 = 0; k0 < K; k0 += 16) {
        float4 av = *(const float4*)(A + (size_t)(bm + arow) * K + k0 + acol);
        As[acol + 0][arow] = av.x; As[acol + 1][arow] = av.y;
        As[acol + 2][arow] = av.z; As[acol + 3][arow] = av.w;
        *(float4*)(&Bs[brow][bcol]) = *(const float4*)(W + (size_t)(k0 + brow) * N + bn + bcol);
        __syncthreads();
#pragma unroll
        for (int k = 0; k < 16; k++) {
            float4 a4 = *(const float4*)(&As[k][ty << 2]);
            float4 b4 = *(const float4*)(&Bs[k][tx << 2]);
            acc[0][0] += a4.x * b4.x; acc[0][1] += a4.x * b4.y; acc[0][2] += a4.x * b4.z; acc[0][3] += a4.x * b4.w;
            acc[1][0] += a4.y * b4.x; acc[1][1] += a4.y * b4.y; acc[1][2] += a4.y * b4.z; acc[1][3] += a4.y * b4.w;
            acc[2][0] += a4.z * b4.x; acc[2][1] += a4.z * b4.y; acc[2][2] += a4.z * b4.z; acc[2][3] += a4.z * b4.w;
            acc[3][0] += a4.w * b4.x; acc[3][1] += a4.w * b4.y; acc[3][2] += a4.w * b4.z; acc[3][3] += a4.w * b4.w;
        }
        __syncthreads();
    }
#pragma unroll
    for (int i = 0; i < 4; i++) {
        int row = bm + (ty << 2) + i;
        int col = bn + (tx << 2);
        float vj[4];
#pragma unroll
        for (int j = 0; j < 4; j++) {
            float v = acc[i][j] + bias[col + j];
            if (ACT == 1) {
                float inner = 0.7978845608028654f * (v + 0.044715f * v * v * v);
                v = 0.5f * v * (1.0f + tanhf(inner));
            } else if (ACT == 2) {
                v = tanhf(v);
            }
            if (resid) v += resid[(size_t)row * N + col + j];
            vj[j] = v;
        }
        float4 r = make_float4(vj[0], vj[1], vj[2], vj[3]);
        *(float4*)(C + (size_t)row * N + col) = r;
    }
}

// dash GEMM: out[bh, s, m] = (row_q . proj_m)*DN - diag_row, for q (z<16) and k (z>=16).
// For k additionally writes per-block max to pmax. Tile 64 s x 64 m, K=64 (full DH).
__global__ __launch_bounds__(256) void phi_dash_kernel(
    const float* __restrict__ q, const float* __restrict__ kq,
    const float* __restrict__ proj, float* __restrict__ dq,
    float* __restrict__ dk, float* __restrict__ pmax)
{
    __shared__ float As[64][68];
    __shared__ float Bs[64][68];
    __shared__ float diag_s[64];
    __shared__ float sred[4];
    int t = threadIdx.x;
    int m0 = blockIdx.x * 64;
    int s0 = blockIdx.y * 64;
    int z = blockIdx.z;
    bool is_k = z >= 16;
    int bh = z & 15, b = bh >> 2, h = bh & 3;
    const float* src = (is_k ? kq : q) + ((size_t)(b * 4096 + s0) * 256) + h * 64;

    int arow = t >> 2, acol = (t & 3) * 16;
    // A: 64 rows x 64 k, stored transposed As[k][row]; fused row sum-of-squares
    float ss = 0.f;
#pragma unroll
    for (int j = 0; j < 4; j++) {
        float4 a = *(const float4*)(src + (size_t)arow * 256 + acol + j * 4);
        As[acol + j * 4 + 0][arow] = a.x; As[acol + j * 4 + 1][arow] = a.y;
        As[acol + j * 4 + 2][arow] = a.z; As[acol + j * 4 + 3][arow] = a.w;
        ss += a.x * a.x + a.y * a.y + a.z * a.z + a.w * a.w;
    }
    ss += __shfl_xor(ss, 1); ss += __shfl_xor(ss, 2);
    if ((t & 3) == 0) diag_s[arow] = DIAGC * ss;
    // B: proj rows m0..m0+63 (guard m<266), transposed Bs[k][m]
    bool bvalid = (m0 + arow) < 266;
    const float* pr = proj + (size_t)(m0 + arow) * 64 + acol;
#pragma unroll
    for (int j = 0; j < 4; j++) {
        float4 p = bvalid ? *(const float4*)(pr + j * 4) : make_float4(0.f, 0.f, 0.f, 0.f);
        Bs[acol + j * 4 + 0][arow] = p.x; Bs[acol + j * 4 + 1][arow] = p.y;
        Bs[acol + j * 4 + 2][arow] = p.z; Bs[acol + j * 4 + 3][arow] = p.w;
    }
    __syncthreads();

    int tx = t & 15, ty = t >> 4;
    float acc[4][4] = {};
#pragma unroll
    for (int kk = 0; kk < 64; kk++) {
        float4 a4 = *(const float4*)(&As[kk][ty << 2]);
        float4 b4 = *(const float4*)(&Bs[kk][tx << 2]);
        acc[0][0] += a4.x * b4.x; acc[0][1] += a4.x * b4.y; acc[0][2] += a4.x * b4.z; acc[0][3] += a4.x * b4.w;
        acc[1][0] += a4.y * b4.x; acc[1][1] += a4.y * b4.y; acc[1][2] += a4.y * b4.z; acc[1][3] += a4.y * b4.w;
        acc[2][0] += a4.z * b4.x; acc[2][1] += a4.z * b4.y; acc[2][2] += a4.z * b4.z; acc[2][3] += a4.z * b4.w;
        acc[3][0] += a4.w * b4.x; acc[3][1] += a4.w * b4.y; acc[3][2] += a4.w * b4.z; acc[3][3] += a4.w * b4.w;
    }

    float* dst = (is_k ? dk : dq);
    float lm = -1e30f;
#pragma unroll
    for (int i = 0; i < 4; i++) {
        int r = (ty << 2) + i;
        float dg = diag_s[r];
        size_t rowbase = ((size_t)bh * 4096 + s0 + r) * 266;
#pragma unroll
        for (int j = 0; j < 4; j++) {
            int m = m0 + (tx << 2) + j;
            if (m < 266) {
                float v = acc[i][j] * DN - dg;
                dst[rowbase + m] = v;
                lm = fmaxf(lm, v);
            }
        }
    }
    lm = wredmax(lm);
    if ((t & 63) == 0) sred[t >> 6] = lm;
    __syncthreads();
    if (is_k && t == 0)
        pmax[(z - 16) * 320 + blockIdx.y * 5 + blockIdx.x] =
            fmaxf(fmaxf(sred[0], sred[1]), fmaxf(sred[2], sred[3]));
}

// q pass2: per row max over 266, then exp. One wave per row, in-place.
__global__ __launch_bounds__(256) void phi_q2_kernel(float* __restrict__ qp)
{
    int t = threadIdx.x;
    int w = t >> 6, lane = t & 63;
    size_t row = (size_t)blockIdx.x * 4 + w;
    float* p = qp + row * 266;
    float v[5];
    float lm = -1e30f;
#pragma unroll
    for (int j = 0; j < 5; j++) {
        int m = lane + j * 64;
        v[j] = (m < 266) ? p[m] : -1e30f;
        lm = fmaxf(lm, v[j]);
    }
    lm = wredmax(lm);
#pragma unroll
    for (int j = 0; j < 5; j++) {
        int m = lane + j * 64;
        if (m < 266) p[m] = RATIO * (expf(v[j] - lm) + FEPS);
    }
}

__global__ __launch_bounds__(256) void reduce_max_kernel(
    const float* __restrict__ pmax, float* __restrict__ stab, int n)
{
    __shared__ float sred[4];
    int t = threadIdx.x;
    float m = -1e30f;
    for (int i = t; i < n; i += 256) m = fmaxf(m, pmax[i]);
    m = wredmax(m);
    if ((t & 63) == 0) sred[t >> 6] = m;
    __syncthreads();
    if (t == 0) stab[0] = fmaxf(fmaxf(sred[0], sred[1]), fmaxf(sred[2], sred[3]));
}

// k pass2: elementwise exp with global stabilizer (diag already folded in)
__global__ __launch_bounds__(256) void phi_k2_kernel(
    float* __restrict__ dash, const float* __restrict__ stab, int total)
{
    int i = blockIdx.x * 256 + threadIdx.x;
    if (i >= total) return;
    dash[i] = RATIO * (expf(dash[i] - stab[0]) + FEPS);
}

// ksum[bh,m] = sum_s kp[bh,s,m]  (s split across blockIdx.z, atomic combine)
__global__ __launch_bounds__(256) void ksum_kernel(
    const float* __restrict__ kp, float* __restrict__ ksum)
{
    int m = blockIdx.x * 256 + threadIdx.x;
    if (m >= 266) return;
    int bh = blockIdx.y;
    int s0 = blockIdx.z * 256;
    float s = 0.f;
    size_t base = ((size_t)(bh << 12) + s0) * 266 + m;
    for (int i = 0; i < 256; i++) s += kp[base + (size_t)i * 266];
    atomicAdd(&ksum[bh * 266 + m], s);
}

// ctx[bh,m,e] += sum_s kp[bh,s,m] * v[b,s,h*64+e]
__global__ __launch_bounds__(256) void ctx_kernel(
    const float* __restrict__ kp, const float* __restrict__ v, float* __restrict__ ctx)
{
    __shared__ float ks[32][32];
    __shared__ float vs[32][64];
    int t = threadIdx.x;
    int m0 = blockIdx.x * 32;
    int bh = blockIdx.y;
    int b = bh >> 2, h = bh & 3;
    int s0 = blockIdx.z * 512;
    int e = t & 63, mg = t >> 6;
    float acc[8] = {};
    int ml = t & 31, sl = t >> 5;
    for (int st = 0; st < 512; st += 32) {
#pragma unroll
        for (int p = 0; p < 4; p++) {
            int ss = sl + p * 8;
            int m = m0 + ml;
            ks[ss][ml] = (m < 266) ? kp[((size_t)(bh << 12) + s0 + st + ss) * 266 + m] : 0.f;
        }
#pragma unroll
        for (int p = 0; p < 8; p++) {
            int ss = (t >> 6) + p * 4;
            vs[ss][e] = v[((size_t)(b << 12) + s0 + st + ss) * 256 + (h << 6) + e];
        }
        __syncthreads();
#pragma unroll
        for (int ss = 0; ss < 32; ss++) {
            float vv = vs[ss][e];
#pragma unroll
            for (int j = 0; j < 8; j++) acc[j] += ks[ss][mg * 8 + j] * vv;
        }
        __syncthreads();
    }
#pragma unroll
    for (int j = 0; j < 8; j++) {
        int m = m0 + mg * 8 + j;
        if (m < 266) atomicAdd(&ctx[((size_t)bh * 266 + m) * 64 + e], acc[j]);
    }
}

// out[s,e] = (qp[s,:] @ ctx[:,e]) / (qp[s,:].ksum)  — tiled GEMM, 64 s x 64 e per block
__global__ __launch_bounds__(256) void attn_gemm_kernel(
    const float* __restrict__ qp, const float* __restrict__ ksum,
    const float* __restrict__ ctx, float* __restrict__ outab)
{
    __shared__ float As[16][68];
    __shared__ float Bs[16][68];
    __shared__ float ksum_s[266];
    __shared__ float dinv_s[64];
    int t = threadIdx.x;
    int s0 = blockIdx.x * 64;
    int bh = blockIdx.y;
    int b = bh >> 2, h = bh & 3;
    ksum_s[t] = (t < 266) ? ksum[bh * 266 + t] : 0.f;
    if (t < 10) ksum_s[256 + t] = ksum[bh * 266 + 256 + t];
    __syncthreads();

    int arow = t >> 2, acol = (t & 3) * 4;
    int brow = t >> 4, bcol = (t & 15) * 4;
    int tx = t & 15, ty = t >> 4;
    const float* qrow = qp + ((size_t)bh * 4096 + s0 + arow) * 266;
    float dpart = 0.f;
    float acc[4][4] = {};
    for (int m0 = 0; m0 < 272; m0 += 16) {
        // A: 64 rows x 16 k (float2 loads; 266 is even, rows only 8B-aligned)
#pragma unroll
        for (int c = 0; c < 4; c += 2) {
            int m = m0 + acol + c;
            float2 v2 = (m < 266) ? *(const float2*)(qrow + m) : make_float2(0.f, 0.f);
            As[acol + c][arow] = v2.x;
            As[acol + c + 1][arow] = v2.y;
            if (m < 266) dpart += v2.x * ksum_s[m] + v2.y * ksum_s[m + 1];
        }
        // B: 16 k x 64 e
        {
            int m = m0 + brow;
            float4 bv = (m < 266) ? *(const float4*)(ctx + ((size_t)bh * 266 + m) * 64 + bcol)
                                  : make_float4(0.f, 0.f, 0.f, 0.f);
            *(float4*)(&Bs[brow][bcol]) = bv;
        }
        __syncthreads();
#pragma unroll
        for (int kk = 0; kk < 16; kk++) {
            float4 a4 = *(const float4*)(&As[kk][ty << 2]);
            float4 b4 = *(const float4*)(&Bs[kk][tx << 2]);
            acc[0][0] += a4.x * b4.x; acc[0][1] += a4.x * b4.y; acc[0][2] += a4.x * b4.z; acc[0][3] += a4.x * b4.w;
            acc[1][0] += a4.y * b4.x; acc[1][1] += a4.y * b4.y; acc[1][2] += a4.y * b4.z; acc[1][3] += a4.y * b4.w;
            acc[2][0] += a4.z * b4.x; acc[2][1] += a4.z * b4.y; acc[2][2] += a4.z * b4.z; acc[2][3] += a4.z * b4.w;
            acc[3][0] += a4.w * b4.x; acc[3][1] += a4.w * b4.y; acc[3][2] += a4.w * b4.z; acc[3][3] += a4.w * b4.w;
        }
        __syncthreads();
    }
    dpart += __shfl_xor(dpart, 1); dpart += __shfl_xor(dpart, 2);
    if ((t & 3) == 0) dinv_s[arow] = dpart;
    __syncthreads();
#pragma unroll
    for (int i = 0; i < 4; i++) {
        int r = (ty << 2) + i;
        float inv = 1.0f / dinv_s[r];
        float4 o = make_float4(acc[i][0] * inv, acc[i][1] * inv, acc[i][2] * inv, acc[i][3] * inv);
        *(float4*)(outab + ((size_t)(b * 4096 + s0 + r)) * 256 + h * 64 + (tx << 2)) = o;
    }
}

// alpha[row] = exp(e_row · p2w + p2b) * mask[row]
__global__ __launch_bounds__(256) void pool_score_kernel(
    const float* __restrict__ e, const float* __restrict__ p2w,
    const float* __restrict__ p2b, const float* __restrict__ mask, float* __restrict__ alpha)
{
    __shared__ float sred[4];
    int row = blockIdx.x, t = threadIdx.x;
    float p = e[(size_t)row * 256 + t] * p2w[t];
    p = wredsum(p);
    if ((t & 63) == 0) sred[t >> 6] = p;
    __syncthreads();
    if (t == 0) {
        float sc = sred[0] + sred[1] + sred[2] + sred[3] + p2b[0];
        alpha[row] = expf(sc) * mask[row];
    }
}

__global__ __launch_bounds__(256) void pool_denom_kernel(
    const float* __restrict__ alpha, float* __restrict__ denomb)
{
    __shared__ float sred[4];
    int b = blockIdx.x, t = threadIdx.x;
    float p = 0.f;
    for (int s = t; s < 4096; s += 256) p += alpha[b * 4096 + s];
    p = wredsum(p);
    if ((t & 63) == 0) sred[t >> 6] = p;
    __syncthreads();
    if (t == 0) denomb[b] = sred[0] + sred[1] + sred[2] + sred[3] + 1e-8f;
}

__global__ __launch_bounds__(256) void pool_out_kernel(
    const float* __restrict__ x, const float* __restrict__ alpha,
    const float* __restrict__ denomb, float* __restrict__ out)
{
    int b = blockIdx.x, chunk = blockIdx.y, t = threadIdx.x;
    float inv = 1.0f / denomb[b];
    float acc = 0.f;
    int s0 = chunk * 128;
    for (int s = s0; s < s0 + 128; s++)
        acc += x[((size_t)(b << 12) + s) * 256 + t] * alpha[(b << 12) + s];
    atomicAdd(&out[b * 256 + t], acc * inv);
}

extern "C" void kernel_launch(void* const* d_in, const int* in_sizes, int n_in,
                              void* d_out, int out_size, void* d_ws, size_t ws_size,
                              hipStream_t stream)
{
    const float* input_embs = (const float*)d_in[0];
    const float* mask  = (const float*)d_in[1];
    const float* pos   = (const float*)d_in[2];
    const float* ln_g  = (const float*)d_in[3];
    const float* ln_b  = (const float*)d_in[4];
    const float* proj  = (const float*)d_in[5];
    const float* Wq = (const float*)d_in[6];  const float* bq = (const float*)d_in[7];
    const float* Wk = (const float*)d_in[8];  const float* bk = (const float*)d_in[9];
    const float* Wv = (const float*)d_in[10]; const float* bv = (const float*)d_in[11];
    const float* Wo = (const float*)d_in[12]; const float* bo = (const float*)d_in[13];
    const float* ln1g = (const float*)d_in[14]; const float* ln1b = (const float*)d_in[15];
    const float* W1 = (const float*)d_in[16]; const float* b1 = (const float*)d_in[17];
    const float* W2 = (const float*)d_in[18]; const float* b2 = (const float*)d_in[19];
    const float* ln2g = (const float*)d_in[20]; const float* ln2b = (const float*)d_in[21];
    const float* p1w = (const float*)d_in[22]; const float* p1b = (const float*)d_in[23];
    const float* p2w = (const float*)d_in[24]; const float* p2b = (const float*)d_in[25];
    float* out = (float*)d_out;
    char* ws = (char*)d_ws;

    size_t off = 0;
    auto alloc = [&](size_t bytes) { size_t o = off; off += WS_ALIGN(bytes); return o; };
    float* xbuf  = (float*)(ws + alloc(16384ull * 256 * 4));
    float* hbuf  = (float*)(ws + alloc(16384ull * 256 * 4));
    float* qbuf  = (float*)(ws + alloc(16384ull * 256 * 4));
    float* kbuf  = (float*)(ws + alloc(16384ull * 256 * 4));
    float* vbuf  = (float*)(ws + alloc(16384ull * 256 * 4));
    size_t qp_bytes = 4ull * 4 * 4096 * 266 * 4;          // 69,730,304 B
    float* qpbuf = (float*)(ws + alloc(qp_bytes));        // also FFN mid (needs 67,108,864 B)
    float* kpbuf = (float*)(ws + alloc(qp_bytes));
    float* pmaxb = (float*)(ws + alloc(5120ull * 4));
    float* stabb = (float*)(ws + alloc(256));
    size_t ksum_off = alloc(16ull * 266 * 4);
    float* ksumb = (float*)(ws + ksum_off);
    size_t ctx_off = alloc(16ull * 266 * 64 * 4);
    float* ctxb = (float*)(ws + ctx_off);
    float* alphab = (float*)(ws + alloc(16384ull * 4));
    float* denomb = (float*)(ws + alloc(256));
    float* midbuf = qpbuf;
    size_t ksum_ctx_bytes = (ctx_off + WS_ALIGN(16ull * 266 * 64 * 4)) - ksum_off;

    // x = LN(input + pos)
    add_ln_kernel<<<16384, 256, 0, stream>>>(input_embs, pos, ln_g, ln_b, xbuf);

    for (int i = 0; i < 4; i++) {
        const float* pj = proj + (size_t)i * 266 * 64;
        add_ln_kernel<<<16384, 256, 0, stream>>>(xbuf, nullptr, ln1g + i * 256, ln1b + i * 256, hbuf);
        gemm_kernel<0><<<dim3(4, 256), 256, 0, stream>>>(hbuf, Wq + (size_t)i * 65536, bq + i * 256, nullptr, qbuf, 16384, 256, 256);
        gemm_kernel<0><<<dim3(4, 256), 256, 0, stream>>>(hbuf, Wk + (size_t)i * 65536, bk + i * 256, nullptr, kbuf, 16384, 256, 256);
        gemm_kernel<0><<<dim3(4, 256), 256, 0, stream>>>(hbuf, Wv + (size_t)i * 65536, bv + i * 256, nullptr, vbuf, 16384, 256, 256);
        phi_dash_kernel<<<dim3(5, 64, 32), 256, 0, stream>>>(qbuf, kbuf, pj, qpbuf, kpbuf, pmaxb);
        reduce_max_kernel<<<1, 256, 0, stream>>>(pmaxb, stabb, 5120);
        phi_q2_kernel<<<16384, 256, 0, stream>>>(qpbuf);
        phi_k2_kernel<<<(4 * 4 * 4096 * 266 + 255) / 256, 256, 0, stream>>>(kpbuf, stabb, 4 * 4 * 4096 * 266);
        hipMemsetAsync(ws + ksum_off, 0, ksum_ctx_bytes, stream);
        ksum_kernel<<<dim3(2, 16, 16), 256, 0, stream>>>(kpbuf, ksumb);
        ctx_kernel<<<dim3(9, 16, 8), 256, 0, stream>>>(kpbuf, vbuf, ctxb);
        attn_gemm_kernel<<<dim3(64, 16), 256, 0, stream>>>(qpbuf, ksumb, ctxb, hbuf);
        gemm_kernel<0><<<dim3(4, 256), 256, 0, stream>>>(hbuf, Wo + (size_t)i * 65536, bo + i * 256, xbuf, xbuf, 16384, 256, 256);
        add_ln_kernel<<<16384, 256, 0, stream>>>(xbuf, nullptr, ln2g + i * 256, ln2b + i * 256, hbuf);
        gemm_kernel<1><<<dim3(16, 256), 256, 0, stream>>>(hbuf, W1 + (size_t)i * 262144, b1 + i * 1024, nullptr, midbuf, 16384, 1024, 256);
        gemm_kernel<0><<<dim3(4, 256), 256, 0, stream>>>(midbuf, W2 + (size_t)i * 262144, b2 + i * 256, xbuf, xbuf, 16384, 256, 1024);
    }

    // Attention pooling
    gemm_kernel<2><<<dim3(4, 256), 256, 0, stream>>>(xbuf, p1w, p1b, nullptr, hbuf, 16384, 256, 256);
    pool_score_kernel<<<16384, 256, 0, stream>>>(hbuf, p2w, p2b, mask, alphab);
    pool_denom_kernel<<<4, 256, 0, stream>>>(alphab, denomb);
    hipMemsetAsync(d_out, 0, (size_t)out_size * sizeof(float), stream);
    pool_out_kernel<<<dim3(4, 32), 256, 0, stream>>>(xbuf, alphab, denomb, out);
}

// Round 4
// 1205.097 us; speedup vs baseline: 7.3047x; 7.1666x over previous
//
#include <hip/hip_runtime.h>
#include <math.h>

// Performer encoder on MI355X: B=4, S=4096, D=256, H=4, DH=64, L=4, M=266.
// bf16 MFMA (16x16x32) for all GEMMs, fp32 residual stream / LN / softmax logic.
// Workspace budget ~201.5 MB (dkT eliminated via k-dash recompute; proven-safe < 224 MB).

#define WS_ALIGN(x) (((x) + 255) & ~(size_t)255)

#define DN 0.35355339059327373f      // 64^-0.25
#define DIAGC 0.0625f                 // 0.5 * 64^-0.5
#define RATIO 0.06131393394849658f    // 266^-0.5
#define FEPS 1e-4f

typedef __attribute__((__ext_vector_type__(8))) __bf16 bf16x8;
typedef __attribute__((__ext_vector_type__(4))) float f32x4;

__device__ __forceinline__ float wredsum(float v) {
    v += __shfl_xor(v, 32); v += __shfl_xor(v, 16); v += __shfl_xor(v, 8);
    v += __shfl_xor(v, 4);  v += __shfl_xor(v, 2);  v += __shfl_xor(v, 1);
    return v;
}
__device__ __forceinline__ float wredmax(float v) {
    v = fmaxf(v, __shfl_xor(v, 32)); v = fmaxf(v, __shfl_xor(v, 16));
    v = fmaxf(v, __shfl_xor(v, 8));  v = fmaxf(v, __shfl_xor(v, 4));
    v = fmaxf(v, __shfl_xor(v, 2));  v = fmaxf(v, __shfl_xor(v, 1));
    return v;
}

__device__ __forceinline__ unsigned short f2bf(float f) {
    unsigned u = __builtin_bit_cast(unsigned, f);
    return (unsigned short)((u + 0x7fffu + ((u >> 16) & 1u)) >> 16);
}
__device__ __forceinline__ float bf2f(unsigned short x) {
    return __builtin_bit_cast(float, (unsigned)x << 16);
}
__device__ __forceinline__ float blo(unsigned x) { return __builtin_bit_cast(float, x << 16); }
__device__ __forceinline__ float bhi(unsigned x) { return __builtin_bit_cast(float, x & 0xffff0000u); }
__device__ __forceinline__ float sumsq8(uint4 u) {
    float s = 0.f;
    s += blo(u.x)*blo(u.x) + bhi(u.x)*bhi(u.x);
    s += blo(u.y)*blo(u.y) + bhi(u.y)*bhi(u.y);
    s += blo(u.z)*blo(u.z) + bhi(u.z)*bhi(u.z);
    s += blo(u.w)*blo(u.w) + bhi(u.w)*bhi(u.w);
    return s;
}
__device__ __forceinline__ float sum8(uint4 u) {
    return blo(u.x)+bhi(u.x)+blo(u.y)+bhi(u.y)+blo(u.z)+bhi(u.z)+blo(u.w)+bhi(u.w);
}

// ---------------- LayerNorm (fp32 in, fp32 or bf16 out) ----------------
template <bool OBF>
__global__ __launch_bounds__(256) void add_ln_kernel(
    const float* __restrict__ in, const float* __restrict__ pos,
    const float* __restrict__ g, const float* __restrict__ bta,
    float* __restrict__ outf, unsigned short* __restrict__ outb)
{
    int row = blockIdx.x, t = threadIdx.x;
    __shared__ float sred[4];
    float v = in[(size_t)row * 256 + t];
    if (pos) v += pos[(size_t)(row & 4095) * 256 + t];
    float s = wredsum(v);
    if ((t & 63) == 0) sred[t >> 6] = s;
    __syncthreads();
    float mean = (sred[0] + sred[1] + sred[2] + sred[3]) * (1.0f / 256.0f);
    float d = v - mean;
    __syncthreads();
    float sq = wredsum(d * d);
    if ((t & 63) == 0) sred[t >> 6] = sq;
    __syncthreads();
    float var = (sred[0] + sred[1] + sred[2] + sred[3]) * (1.0f / 256.0f);
    float y = d * rsqrtf(var + 1e-12f) * g[t] + bta[t];
    if (OBF) outb[(size_t)row * 256 + t] = f2bf(y);
    else     outf[(size_t)row * 256 + t] = y;
}

// ---------------- weight cast/transpose: fp32 [R][C] -> bf16 [C][R] ----------------
__global__ __launch_bounds__(256) void cast_transpose_kernel(
    const float* __restrict__ in, unsigned short* __restrict__ out, int R, int C)
{
    __shared__ float tile[32][33];
    size_t zo = (size_t)blockIdx.z * R * C;
    int c0 = blockIdx.x * 32, r0 = blockIdx.y * 32;
    int t = threadIdx.x, tc = t & 31, tr = t >> 5;
#pragma unroll
    for (int j = 0; j < 4; j++)
        tile[tr + j * 8][tc] = in[zo + (size_t)(r0 + tr + j * 8) * C + c0 + tc];
    __syncthreads();
#pragma unroll
    for (int j = 0; j < 4; j++) {
        int cc = tr + j * 8, rr = tc;
        out[zo + (size_t)(c0 + cc) * R + r0 + rr] = f2bf(tile[rr][cc]);
    }
}

// fp32 -> bf16 elementwise (n4 = count/4)
__global__ __launch_bounds__(256) void cast_row_kernel(
    const float4* __restrict__ in, ushort4* __restrict__ out, int n4)
{
    int i = blockIdx.x * 256 + threadIdx.x;
    if (i >= n4) return;
    float4 v = in[i];
    ushort4 o; o.x = f2bf(v.x); o.y = f2bf(v.y); o.z = f2bf(v.z); o.w = f2bf(v.w);
    out[i] = o;
}

// ---------------- generic bf16 MFMA GEMM ----------------
// C[M,N] = A[M,K] @ Bt[N,K]^T + bias, epilogues:
// EPI 1: +resid, fp32 out [M][N]
// EPI 2: gelu(tanh), bf16 out [M][N]
// EPI 3: bf16 out head-split [bh][s][64]   (N==256)
// EPI 4: bf16 out v-transposed [bh][e][s]  (N==256)
// EPI 5: tanh, bf16 out [M][N]
template <int EPI>
__global__ __launch_bounds__(256) void gemm_bf16_kernel(
    const unsigned short* __restrict__ A, const unsigned short* __restrict__ Bt,
    const float* __restrict__ bias, const float* __restrict__ resid,
    void* __restrict__ Cout, int N, int K)
{
    __shared__ uint4 As[128][5];
    __shared__ uint4 Bs[64][5];
    int t = threadIdx.x;
    int bm = blockIdx.y * 128, bn = blockIdx.x * 64;
    int w = t >> 6, l = t & 63, lm16 = l & 15, quad = l >> 4;
    int ar = t >> 1, ak = (t & 1) * 16;
    int br = t >> 2, bk = (t & 3) * 8;
    const unsigned short* Ab = A + (size_t)(bm + ar) * K + ak;
    const unsigned short* Bb = Bt + (size_t)(bn + br) * K + bk;
    f32x4 acc[2][4] = {};
    for (int k0 = 0; k0 < K; k0 += 32) {
        uint4 a0 = *(const uint4*)(Ab + k0);
        uint4 a1 = *(const uint4*)(Ab + k0 + 8);
        uint4 b0 = *(const uint4*)(Bb + k0);
        __syncthreads();
        As[ar][(ak >> 3)] = a0; As[ar][(ak >> 3) + 1] = a1;
        Bs[br][bk >> 3] = b0;
        __syncthreads();
        bf16x8 af[2], bfr[4];
        af[0] = *(const bf16x8*)&As[w * 32 + lm16][quad];
        af[1] = *(const bf16x8*)&As[w * 32 + 16 + lm16][quad];
#pragma unroll
        for (int j = 0; j < 4; j++) bfr[j] = *(const bf16x8*)&Bs[j * 16 + lm16][quad];
#pragma unroll
        for (int i = 0; i < 2; i++)
#pragma unroll
            for (int j = 0; j < 4; j++)
                acc[i][j] = __builtin_amdgcn_mfma_f32_16x16x32_bf16(af[i], bfr[j], acc[i][j], 0, 0, 0);
    }
    float* Cf = (float*)Cout;
    unsigned short* Cb = (unsigned short*)Cout;
#pragma unroll
    for (int i = 0; i < 2; i++)
#pragma unroll
        for (int j = 0; j < 4; j++) {
            int col = bn + j * 16 + lm16;
            float bsv = bias[col];
#pragma unroll
            for (int r = 0; r < 4; r++) {
                int row = bm + w * 32 + i * 16 + quad * 4 + r;
                float v = acc[i][j][r] + bsv;
                if (EPI == 1) {
                    Cf[(size_t)row * N + col] = v + resid[(size_t)row * N + col];
                } else if (EPI == 2) {
                    float inner = 0.7978845608028654f * (v + 0.044715f * v * v * v);
                    float gl = 0.5f * v * (1.0f + tanhf(inner));
                    Cb[(size_t)row * N + col] = f2bf(gl);
                } else if (EPI == 3) {
                    int b = row >> 12, s = row & 4095, h = col >> 6, e = col & 63;
                    Cb[((size_t)((b << 2) + h) * 4096 + s) * 64 + e] = f2bf(v);
                } else if (EPI == 4) {
                    int b = row >> 12, s = row & 4095, h = col >> 6, e = col & 63;
                    Cb[((size_t)((b << 2) + h) * 64 + e) * 4096 + s] = f2bf(v);
                } else if (EPI == 5) {
                    Cb[(size_t)row * N + col] = f2bf(tanhf(v));
                }
            }
        }
}

// ---------------- phi dash MFMA (tile 128 s x 64 m, K=64) ----------------
// dash[s][m] = (x . proj_m)*DN - diag_s
// MODE 0: q-side, store dash fp32 -> dq[bh][s][272]
// MODE 1: k-side, per-block max only -> pmax
// MODE 2: k-side, recompute dash, kpT[bh][m][s] = bf16(RATIO*(exp(dash - stab) + eps))
template <int MODE>
__global__ __launch_bounds__(256) void phi_mfma_kernel(
    const unsigned short* __restrict__ src0, const unsigned short* __restrict__ projbf,
    float* __restrict__ dq, unsigned short* __restrict__ kpT,
    const float* __restrict__ stab, float* __restrict__ pmax)
{
    __shared__ uint4 As[128][9];
    __shared__ uint4 Bs[64][9];
    __shared__ float diag_s[128];
    __shared__ float sred[4];
    int t = threadIdx.x;
    int m0 = blockIdx.x * 64;
    int s0 = blockIdx.y * 128;
    int bh = blockIdx.z;
    const unsigned short* src = src0 + ((size_t)bh * 4096 + s0) * 64;
    {
        int row = t >> 1, koff = (t & 1) * 32;
        const uint4* g = (const uint4*)(src + (size_t)row * 64 + koff);
        float ss = 0.f;
#pragma unroll
        for (int i = 0; i < 4; i++) { uint4 u = g[i]; As[row][(koff >> 3) + i] = u; ss += sumsq8(u); }
        ss += __shfl_xor(ss, 1);
        if ((t & 1) == 0) diag_s[row] = DIAGC * ss;
        int brow = t >> 2, bkoff = (t & 3) * 16;
        uint4 zero = {0, 0, 0, 0};
        bool bv = (m0 + brow) < 266;
        const uint4* gp = (const uint4*)(projbf + (size_t)(m0 + brow) * 64 + bkoff);
#pragma unroll
        for (int i = 0; i < 2; i++) Bs[brow][(bkoff >> 3) + i] = bv ? gp[i] : zero;
    }
    __syncthreads();
    int w = t >> 6, l = t & 63, lm16 = l & 15, quad = l >> 4;
    f32x4 acc[2][4] = {};
#pragma unroll
    for (int ks = 0; ks < 2; ks++) {
        bf16x8 af[2], bfr[4];
        af[0] = *(const bf16x8*)&As[w * 32 + lm16][ks * 4 + quad];
        af[1] = *(const bf16x8*)&As[w * 32 + 16 + lm16][ks * 4 + quad];
#pragma unroll
        for (int j = 0; j < 4; j++) bfr[j] = *(const bf16x8*)&Bs[j * 16 + lm16][ks * 4 + quad];
#pragma unroll
        for (int i = 0; i < 2; i++)
#pragma unroll
            for (int j = 0; j < 4; j++)
                acc[i][j] = __builtin_amdgcn_mfma_f32_16x16x32_bf16(af[i], bfr[j], acc[i][j], 0, 0, 0);
    }
    float st = (MODE == 2) ? stab[0] : 0.f;
    float kmax = -1e30f;
#pragma unroll
    for (int i = 0; i < 2; i++)
#pragma unroll
        for (int j = 0; j < 4; j++)
#pragma unroll
            for (int r = 0; r < 4; r++) {
                int m = m0 + j * 16 + lm16;
                if (m >= 272) continue;
                int srow = w * 32 + i * 16 + quad * 4 + r;
                float v = acc[i][j][r] * DN - diag_s[srow];
                int s = s0 + srow;
                if (MODE == 0) {
                    dq[((size_t)bh * 4096 + s) * 272 + m] = v;
                } else if (MODE == 1) {
                    if (m < 266) kmax = fmaxf(kmax, v);
                } else {
                    kpT[((size_t)bh * 272 + m) * 4096 + s] =
                        f2bf(RATIO * (expf(v - st) + FEPS));
                }
            }
    if (MODE == 1) {
        kmax = wredmax(kmax);
        if (l == 0) sred[w] = kmax;
        __syncthreads();
        if (t == 0)
            pmax[((size_t)bh * 32 + blockIdx.y) * 5 + blockIdx.x] =
                fmaxf(fmaxf(sred[0], sred[1]), fmaxf(sred[2], sred[3]));
    }
}

__global__ __launch_bounds__(256) void reduce_max_kernel(
    const float* __restrict__ pmax, float* __restrict__ stab, int n)
{
    __shared__ float sred[4];
    int t = threadIdx.x;
    float m = -1e30f;
    for (int i = t; i < n; i += 256) m = fmaxf(m, pmax[i]);
    m = wredmax(m);
    if ((t & 63) == 0) sred[t >> 6] = m;
    __syncthreads();
    if (t == 0) stab[0] = fmaxf(fmaxf(sred[0], sred[1]), fmaxf(sred[2], sred[3]));
}

// ksum[bh*272+m] = sum_s kpT[bh][m][s]  — one wave per row
__global__ __launch_bounds__(256) void ksum_kernel(
    const unsigned short* __restrict__ kpT, float* __restrict__ ksum)
{
    int t = threadIdx.x, w = t >> 6, l = t & 63;
    int row = blockIdx.x * 4 + w;       // row in [0, 16*272)
    const uint4* src = (const uint4*)(kpT + (size_t)row * 4096);
    float s = 0.f;
#pragma unroll
    for (int it = 0; it < 8; it++) s += sum8(src[l + it * 64]);
    s = wredsum(s);
    if (l == 0) ksum[row] = s;
}

// q pass2: row max + exp -> qp bf16 [bh][s][272] (pad zeroed), denom = qp . ksum
__global__ __launch_bounds__(256) void phi_q2_kernel(
    const float* __restrict__ dq, const float* __restrict__ ksum,
    unsigned short* __restrict__ qp, float* __restrict__ denomb)
{
    __shared__ float ks_s[272];
    int t = threadIdx.x;
    int r0 = blockIdx.x * 4;
    int bh = r0 >> 12;
    ks_s[t] = ksum[bh * 272 + t];
    if (t < 16) ks_s[256 + t] = ksum[bh * 272 + 256 + t];
    __syncthreads();
    int w = t >> 6, l = t & 63;
    size_t row = (size_t)r0 + w;
    const float* src = dq + row * 272;
    float v[5];
    float lm = -1e30f;
#pragma unroll
    for (int j = 0; j < 4; j++) { v[j] = src[l + j * 64]; lm = fmaxf(lm, v[j]); }
    v[4] = 0.f;
    if (l < 16) { v[4] = src[256 + l]; if (l < 10) lm = fmaxf(lm, v[4]); }
    lm = wredmax(lm);
    float d = 0.f;
#pragma unroll
    for (int j = 0; j < 4; j++) {
        int m = l + j * 64;
        float e = RATIO * (expf(v[j] - lm) + FEPS);
        qp[row * 272 + m] = f2bf(e);
        d += e * ks_s[m];
    }
    if (l < 16) {
        int m = 256 + l;
        float e = (m < 266) ? RATIO * (expf(v[4] - lm) + FEPS) : 0.f;
        qp[row * 272 + m] = f2bf(e);
        d += e * ks_s[m];
    }
    d = wredsum(d);
    if (l == 0) denomb[row] = d;
}

// ctx MFMA: ctxT[bh][e][m] += sum_s kpT[bh][m][s] * vT[bh][e][s]  (fp32 atomics, K split)
__global__ __launch_bounds__(256) void ctx_mfma_kernel(
    const unsigned short* __restrict__ kpT, const unsigned short* __restrict__ vT,
    float* __restrict__ ctxT)
{
    __shared__ uint4 As[64][9];
    __shared__ uint4 Bs[64][9];
    int t = threadIdx.x;
    int m0 = blockIdx.x * 64;
    int bh = blockIdx.y;
    int sb = blockIdx.z * 1024;
    int w = t >> 6, l = t & 63, lm16 = l & 15, quad = l >> 4;
    int row = t >> 2, koff = (t & 3) * 16;
    bool av = (m0 + row) < 272;
    const uint4* ga = (const uint4*)(kpT + ((size_t)bh * 272 + m0 + row) * 4096 + sb + koff);
    const uint4* gb = (const uint4*)(vT + ((size_t)bh * 64 + row) * 4096 + sb + koff);
    uint4 zero = {0, 0, 0, 0};
    f32x4 acc[4] = {};
    for (int kc = 0; kc < 16; kc++) {
        uint4 a0 = av ? ga[0] : zero, a1 = av ? ga[1] : zero;
        uint4 b0 = gb[0], b1 = gb[1];
        ga += 8; gb += 8;
        __syncthreads();
        As[row][(koff >> 3)] = a0; As[row][(koff >> 3) + 1] = a1;
        Bs[row][(koff >> 3)] = b0; Bs[row][(koff >> 3) + 1] = b1;
        __syncthreads();
#pragma unroll
        for (int ks = 0; ks < 2; ks++) {
            bf16x8 af = *(const bf16x8*)&As[w * 16 + lm16][ks * 4 + quad];
#pragma unroll
            for (int j = 0; j < 4; j++) {
                bf16x8 bfr = *(const bf16x8*)&Bs[j * 16 + lm16][ks * 4 + quad];
                acc[j] = __builtin_amdgcn_mfma_f32_16x16x32_bf16(af, bfr, acc[j], 0, 0, 0);
            }
        }
    }
#pragma unroll
    for (int j = 0; j < 4; j++)
#pragma unroll
        for (int r = 0; r < 4; r++) {
            int m = m0 + w * 16 + quad * 4 + r;
            if (m < 272)
                atomicAdd(&ctxT[((size_t)bh * 64 + j * 16 + lm16) * 272 + m], acc[j][r]);
        }
}

// attn MFMA: out[s][e] = (qp[s,:] @ ctxT[e,:]) / denom[s] -> abf bf16 [b][s][h*64+e]
__global__ __launch_bounds__(256) void attn_mfma_kernel(
    const unsigned short* __restrict__ qp, const unsigned short* __restrict__ ctxTbf,
    const float* __restrict__ denomb, unsigned short* __restrict__ abf)
{
    __shared__ uint4 As[128][5];
    __shared__ uint4 Bs[64][5];
    int t = threadIdx.x;
    int s0 = blockIdx.x * 128;
    int bh = blockIdx.y; int b = bh >> 2, h = bh & 3;
    int w = t >> 6, l = t & 63, lm16 = l & 15, quad = l >> 4;
    int ar = t >> 1, ak = (t & 1) * 16;
    int br = t >> 2, bk = (t & 3) * 8;
    const unsigned short* Ab = qp + ((size_t)bh * 4096 + s0 + ar) * 272 + ak;
    const unsigned short* Bb = ctxTbf + ((size_t)bh * 64 + br) * 272 + bk;
    uint4 zero = {0, 0, 0, 0};
    f32x4 acc[2][4] = {};
    for (int k0 = 0; k0 < 272; k0 += 32) {
        uint4 a0 = (k0 + ak < 272)     ? *(const uint4*)(Ab + k0)     : zero;
        uint4 a1 = (k0 + ak + 8 < 272) ? *(const uint4*)(Ab + k0 + 8) : zero;
        uint4 b0 = (k0 + bk < 272)     ? *(const uint4*)(Bb + k0)     : zero;
        __syncthreads();
        As[ar][(ak >> 3)] = a0; As[ar][(ak >> 3) + 1] = a1;
        Bs[br][bk >> 3] = b0;
        __syncthreads();
        bf16x8 af[2], bfr[4];
        af[0] = *(const bf16x8*)&As[w * 32 + lm16][quad];
        af[1] = *(const bf16x8*)&As[w * 32 + 16 + lm16][quad];
#pragma unroll
        for (int j = 0; j < 4; j++) bfr[j] = *(const bf16x8*)&Bs[j * 16 + lm16][quad];
#pragma unroll
        for (int i = 0; i < 2; i++)
#pragma unroll
            for (int j = 0; j < 4; j++)
                acc[i][j] = __builtin_amdgcn_mfma_f32_16x16x32_bf16(af[i], bfr[j], acc[i][j], 0, 0, 0);
    }
#pragma unroll
    for (int i = 0; i < 2; i++)
#pragma unroll
        for (int j = 0; j < 4; j++)
#pragma unroll
            for (int r = 0; r < 4; r++) {
                int s = s0 + w * 32 + i * 16 + quad * 4 + r;
                float v = acc[i][j][r] / denomb[(size_t)bh * 4096 + s];
                int e = j * 16 + lm16;
                abf[((size_t)(b * 4096 + s)) * 256 + h * 64 + e] = f2bf(v);
            }
}

// ---------------- pooling ----------------
__global__ __launch_bounds__(256) void pool_score_kernel(
    const unsigned short* __restrict__ e, const float* __restrict__ p2w,
    const float* __restrict__ p2b, const float* __restrict__ mask, float* __restrict__ alpha)
{
    __shared__ float sred[4];
    int row = blockIdx.x, t = threadIdx.x;
    float p = bf2f(e[(size_t)row * 256 + t]) * p2w[t];
    p = wredsum(p);
    if ((t & 63) == 0) sred[t >> 6] = p;
    __syncthreads();
    if (t == 0) {
        float sc = sred[0] + sred[1] + sred[2] + sred[3] + p2b[0];
        alpha[row] = expf(sc) * mask[row];
    }
}

__global__ __launch_bounds__(256) void pool_denom_kernel(
    const float* __restrict__ alpha, float* __restrict__ denomb)
{
    __shared__ float sred[4];
    int b = blockIdx.x, t = threadIdx.x;
    float p = 0.f;
    for (int s = t; s < 4096; s += 256) p += alpha[b * 4096 + s];
    p = wredsum(p);
    if ((t & 63) == 0) sred[t >> 6] = p;
    __syncthreads();
    if (t == 0) denomb[b] = sred[0] + sred[1] + sred[2] + sred[3] + 1e-8f;
}

__global__ __launch_bounds__(256) void pool_out_kernel(
    const float* __restrict__ x, const float* __restrict__ alpha,
    const float* __restrict__ denomb, float* __restrict__ out)
{
    int b = blockIdx.x, chunk = blockIdx.y, t = threadIdx.x;
    float inv = 1.0f / denomb[b];
    float acc = 0.f;
    int s0 = chunk * 128;
    for (int s = s0; s < s0 + 128; s++)
        acc += x[((size_t)(b << 12) + s) * 256 + t] * alpha[(b << 12) + s];
    atomicAdd(&out[b * 256 + t], acc * inv);
}

extern "C" void kernel_launch(void* const* d_in, const int* in_sizes, int n_in,
                              void* d_out, int out_size, void* d_ws, size_t ws_size,
                              hipStream_t stream)
{
    const float* input_embs = (const float*)d_in[0];
    const float* mask  = (const float*)d_in[1];
    const float* pos   = (const float*)d_in[2];
    const float* ln_g  = (const float*)d_in[3];
    const float* ln_b  = (const float*)d_in[4];
    const float* proj  = (const float*)d_in[5];
    const float* Wq = (const float*)d_in[6];  const float* bq = (const float*)d_in[7];
    const float* Wk = (const float*)d_in[8];  const float* bk = (const float*)d_in[9];
    const float* Wv = (const float*)d_in[10]; const float* bv = (const float*)d_in[11];
    const float* Wo = (const float*)d_in[12]; const float* bo = (const float*)d_in[13];
    const float* ln1g = (const float*)d_in[14]; const float* ln1b = (const float*)d_in[15];
    const float* W1 = (const float*)d_in[16]; const float* b1 = (const float*)d_in[17];
    const float* W2 = (const float*)d_in[18]; const float* b2 = (const float*)d_in[19];
    const float* ln2g = (const float*)d_in[20]; const float* ln2b = (const float*)d_in[21];
    const float* p1w = (const float*)d_in[22]; const float* p1b = (const float*)d_in[23];
    const float* p2w = (const float*)d_in[24]; const float* p2b = (const float*)d_in[25];
    float* out = (float*)d_out;
    char* ws = (char*)d_ws;

    size_t off = 0;
    auto alloc = [&](size_t bytes) { size_t o = off; off += WS_ALIGN(bytes); return o; };
    float* xbuf = (float*)(ws + alloc(16384ull * 256 * 4));
    unsigned short* hbf = (unsigned short*)(ws + alloc(16384ull * 256 * 2));   // ln out / attn out / pool tanh
    unsigned short* qbf = (unsigned short*)(ws + alloc(16384ull * 256 * 2));   // also xbf after loop
    unsigned short* kbf = (unsigned short*)(ws + alloc(16384ull * 256 * 2));
    unsigned short* vT  = (unsigned short*)(ws + alloc(16384ull * 256 * 2));
    float* dq  = (float*)(ws + alloc(16ull * 4096 * 272 * 4));                 // also midbf (FFN)
    unsigned short* qp  = (unsigned short*)(ws + alloc(16ull * 4096 * 272 * 2));
    unsigned short* kpT = (unsigned short*)(ws + alloc(16ull * 272 * 4096 * 2));
    size_t ctxT_off = alloc(16ull * 64 * 272 * 4);
    float* ctxT = (float*)(ws + ctxT_off);
    unsigned short* ctxTbf = (unsigned short*)(ws + alloc(16ull * 64 * 272 * 2));
    float* ksum = (float*)(ws + alloc(16ull * 272 * 4));
    float* denomb = (float*)(ws + alloc(65536ull * 4));
    float* pmaxb = (float*)(ws + alloc(2560ull * 4));
    float* stabb = (float*)(ws + alloc(256));
    float* alphab = (float*)(ws + alloc(16384ull * 4));
    float* pdenom = (float*)(ws + alloc(256));
    unsigned short* Wqt = (unsigned short*)(ws + alloc(4ull * 65536 * 2));
    unsigned short* Wkt = (unsigned short*)(ws + alloc(4ull * 65536 * 2));
    unsigned short* Wvt = (unsigned short*)(ws + alloc(4ull * 65536 * 2));
    unsigned short* Wot = (unsigned short*)(ws + alloc(4ull * 65536 * 2));
    unsigned short* W1t = (unsigned short*)(ws + alloc(4ull * 262144 * 2));
    unsigned short* W2t = (unsigned short*)(ws + alloc(4ull * 262144 * 2));
    unsigned short* projbf = (unsigned short*)(ws + alloc(4ull * 17024 * 2));
    unsigned short* p1t = (unsigned short*)(ws + alloc(65536ull * 2));
    unsigned short* midbf = (unsigned short*)dq;
    unsigned short* xbf = qbf;
    unsigned short* abf = hbf;
    // total ~201.5 MB (< 224 MB proven-safe in round 2)

    // ---- weight casts (all layers up front) ----
    cast_transpose_kernel<<<dim3(8, 8, 4), 256, 0, stream>>>(Wq, Wqt, 256, 256);
    cast_transpose_kernel<<<dim3(8, 8, 4), 256, 0, stream>>>(Wk, Wkt, 256, 256);
    cast_transpose_kernel<<<dim3(8, 8, 4), 256, 0, stream>>>(Wv, Wvt, 256, 256);
    cast_transpose_kernel<<<dim3(8, 8, 4), 256, 0, stream>>>(Wo, Wot, 256, 256);
    cast_transpose_kernel<<<dim3(32, 8, 4), 256, 0, stream>>>(W1, W1t, 256, 1024);
    cast_transpose_kernel<<<dim3(8, 32, 4), 256, 0, stream>>>(W2, W2t, 1024, 256);
    cast_transpose_kernel<<<dim3(8, 8, 1), 256, 0, stream>>>(p1w, p1t, 256, 256);
    cast_row_kernel<<<67, 256, 0, stream>>>((const float4*)proj, (ushort4*)projbf, 17024);

    // ---- x = LN(input + pos) ----
    add_ln_kernel<false><<<16384, 256, 0, stream>>>(input_embs, pos, ln_g, ln_b, xbuf, nullptr);

    for (int i = 0; i < 4; i++) {
        const unsigned short* pj = projbf + (size_t)i * 17024;
        // ln1 -> bf16
        add_ln_kernel<true><<<16384, 256, 0, stream>>>(xbuf, nullptr, ln1g + i * 256, ln1b + i * 256, nullptr, hbf);
        // QKV (bf16 MFMA, fused layout epilogues)
        gemm_bf16_kernel<3><<<dim3(4, 128), 256, 0, stream>>>(hbf, Wqt + (size_t)i * 65536, bq + i * 256, nullptr, qbf, 256, 256);
        gemm_bf16_kernel<3><<<dim3(4, 128), 256, 0, stream>>>(hbf, Wkt + (size_t)i * 65536, bk + i * 256, nullptr, kbf, 256, 256);
        gemm_bf16_kernel<4><<<dim3(4, 128), 256, 0, stream>>>(hbf, Wvt + (size_t)i * 65536, bv + i * 256, nullptr, vT, 256, 256);
        // phi: q dash store; k max; k recompute+exp
        phi_mfma_kernel<0><<<dim3(5, 32, 16), 256, 0, stream>>>(qbf, pj, dq, nullptr, nullptr, nullptr);
        phi_mfma_kernel<1><<<dim3(5, 32, 16), 256, 0, stream>>>(kbf, pj, nullptr, nullptr, nullptr, pmaxb);
        reduce_max_kernel<<<1, 256, 0, stream>>>(pmaxb, stabb, 2560);
        phi_mfma_kernel<2><<<dim3(5, 32, 16), 256, 0, stream>>>(kbf, pj, nullptr, kpT, stabb, nullptr);
        ksum_kernel<<<16 * 272 / 4, 256, 0, stream>>>(kpT, ksum);
        phi_q2_kernel<<<16384, 256, 0, stream>>>(dq, ksum, qp, denomb);
        // ctx + attn out
        hipMemsetAsync(ws + ctxT_off, 0, 16ull * 64 * 272 * 4, stream);
        ctx_mfma_kernel<<<dim3(5, 16, 4), 256, 0, stream>>>(kpT, vT, ctxT);
        cast_row_kernel<<<272, 256, 0, stream>>>((const float4*)ctxT, (ushort4*)ctxTbf, 16 * 64 * 272 / 4);
        attn_mfma_kernel<<<dim3(32, 16), 256, 0, stream>>>(qp, ctxTbf, denomb, abf);
        // Wo + residual
        gemm_bf16_kernel<1><<<dim3(4, 128), 256, 0, stream>>>(abf, Wot + (size_t)i * 65536, bo + i * 256, xbuf, xbuf, 256, 256);
        // FFN
        add_ln_kernel<true><<<16384, 256, 0, stream>>>(xbuf, nullptr, ln2g + i * 256, ln2b + i * 256, nullptr, hbf);
        gemm_bf16_kernel<2><<<dim3(16, 128), 256, 0, stream>>>(hbf, W1t + (size_t)i * 262144, b1 + i * 1024, nullptr, midbf, 1024, 256);
        gemm_bf16_kernel<1><<<dim3(4, 128), 256, 0, stream>>>(midbf, W2t + (size_t)i * 262144, b2 + i * 256, xbuf, xbuf, 256, 1024);
    }

    // ---- attention pooling ----
    cast_row_kernel<<<4096, 256, 0, stream>>>((const float4*)xbuf, (ushort4*)xbf, 16384 * 256 / 4);
    gemm_bf16_kernel<5><<<dim3(4, 128), 256, 0, stream>>>(xbf, p1t, p1b, nullptr, hbf, 256, 256);
    pool_score_kernel<<<16384, 256, 0, stream>>>(hbf, p2w, p2b, mask, alphab);
    pool_denom_kernel<<<4, 256, 0, stream>>>(alphab, pdenom);
    hipMemsetAsync(d_out, 0, (size_t)out_size * sizeof(float), stream);
    pool_out_kernel<<<dim3(4, 32), 256, 0, stream>>>(xbuf, alphab, pdenom, out);
}

// Round 5
// 1164.862 us; speedup vs baseline: 7.5570x; 1.0345x over previous
//
#include <hip/hip_runtime.h>
#include <math.h>

// Performer encoder on MI355X: B=4, S=4096, D=256, H=4, DH=64, L=4, M=266.
// bf16 MFMA (16x16x32) everywhere; fp32 residual stream / LN stats / softmax logic.
// Round 5: dash fp32 round-trip eliminated (fused phi-q), ksum fused into k-exp pass,
// QKV merged (N=768), Wo/FFN2 full-row GEMMs with fused residual+LayerNorm epilogues,
// pooling score fused into the pool GEMM. Workspace ~133 MB (256 MiB available).

#define WS_ALIGN(x) (((x) + 255) & ~(size_t)255)

#define DN 0.35355339059327373f      // 64^-0.25
#define DIAGC 0.0625f                 // 0.5 * 64^-0.5
#define RATIO 0.06131393394849658f    // 266^-0.5
#define FEPS 1e-4f

typedef __attribute__((__ext_vector_type__(8))) __bf16 bf16x8;
typedef __attribute__((__ext_vector_type__(4))) float f32x4;

__device__ __forceinline__ float wredsum(float v) {
    v += __shfl_xor(v, 32); v += __shfl_xor(v, 16); v += __shfl_xor(v, 8);
    v += __shfl_xor(v, 4);  v += __shfl_xor(v, 2);  v += __shfl_xor(v, 1);
    return v;
}
__device__ __forceinline__ float wredmax(float v) {
    v = fmaxf(v, __shfl_xor(v, 32)); v = fmaxf(v, __shfl_xor(v, 16));
    v = fmaxf(v, __shfl_xor(v, 8));  v = fmaxf(v, __shfl_xor(v, 4));
    v = fmaxf(v, __shfl_xor(v, 2));  v = fmaxf(v, __shfl_xor(v, 1));
    return v;
}

__device__ __forceinline__ unsigned short f2bf(float f) {
    unsigned u = __builtin_bit_cast(unsigned, f);
    return (unsigned short)((u + 0x7fffu + ((u >> 16) & 1u)) >> 16);
}
__device__ __forceinline__ float blo(unsigned x) { return __builtin_bit_cast(float, x << 16); }
__device__ __forceinline__ float bhi(unsigned x) { return __builtin_bit_cast(float, x & 0xffff0000u); }
__device__ __forceinline__ float sumsq8(uint4 u) {
    float s = 0.f;
    s += blo(u.x)*blo(u.x) + bhi(u.x)*bhi(u.x);
    s += blo(u.y)*blo(u.y) + bhi(u.y)*bhi(u.y);
    s += blo(u.z)*blo(u.z) + bhi(u.z)*bhi(u.z);
    s += blo(u.w)*blo(u.w) + bhi(u.w)*bhi(u.w);
    return s;
}

// ---------------- LayerNorm (fp32 in, fp32 or bf16 out) ----------------
template <bool OBF>
__global__ __launch_bounds__(256) void add_ln_kernel(
    const float* __restrict__ in, const float* __restrict__ pos,
    const float* __restrict__ g, const float* __restrict__ bta,
    float* __restrict__ outf, unsigned short* __restrict__ outb)
{
    int row = blockIdx.x, t = threadIdx.x;
    __shared__ float sred[4];
    float v = in[(size_t)row * 256 + t];
    if (pos) v += pos[(size_t)(row & 4095) * 256 + t];
    float s = wredsum(v);
    if ((t & 63) == 0) sred[t >> 6] = s;
    __syncthreads();
    float mean = (sred[0] + sred[1] + sred[2] + sred[3]) * (1.0f / 256.0f);
    float d = v - mean;
    __syncthreads();
    float sq = wredsum(d * d);
    if ((t & 63) == 0) sred[t >> 6] = sq;
    __syncthreads();
    float var = (sred[0] + sred[1] + sred[2] + sred[3]) * (1.0f / 256.0f);
    float y = d * rsqrtf(var + 1e-12f) * g[t] + bta[t];
    if (OBF) outb[(size_t)row * 256 + t] = f2bf(y);
    else     outf[(size_t)row * 256 + t] = y;
}

// ---------------- weight cast/transpose: fp32 [R][C] -> bf16 [C][R] ----------------
__global__ __launch_bounds__(256) void cast_transpose_kernel(
    const float* __restrict__ in, unsigned short* __restrict__ out, int R, int C)
{
    __shared__ float tile[32][33];
    size_t zo = (size_t)blockIdx.z * R * C;
    int c0 = blockIdx.x * 32, r0 = blockIdx.y * 32;
    int t = threadIdx.x, tc = t & 31, tr = t >> 5;
#pragma unroll
    for (int j = 0; j < 4; j++)
        tile[tr + j * 8][tc] = in[zo + (size_t)(r0 + tr + j * 8) * C + c0 + tc];
    __syncthreads();
#pragma unroll
    for (int j = 0; j < 4; j++) {
        int cc = tr + j * 8, rr = tc;
        out[zo + (size_t)(c0 + cc) * R + r0 + rr] = f2bf(tile[rr][cc]);
    }
}

// fp32 -> bf16 elementwise (n4 = count/4)
__global__ __launch_bounds__(256) void cast_row_kernel(
    const float4* __restrict__ in, ushort4* __restrict__ out, int n4)
{
    int i = blockIdx.x * 256 + threadIdx.x;
    if (i >= n4) return;
    float4 v = in[i];
    ushort4 o; o.x = f2bf(v.x); o.y = f2bf(v.y); o.z = f2bf(v.z); o.w = f2bf(v.w);
    out[i] = o;
}

// ---------------- fused QKV GEMM (N=768 over q|k|v), K=256 ----------------
// q,k -> head-split bf16 [bh][s][64]; v -> transposed bf16 [bh][e][s]
__global__ __launch_bounds__(256) void qkv_kernel(
    const unsigned short* __restrict__ A,
    const unsigned short* __restrict__ Wqt, const unsigned short* __restrict__ Wkt,
    const unsigned short* __restrict__ Wvt,
    const float* __restrict__ bq, const float* __restrict__ bk, const float* __restrict__ bv,
    unsigned short* __restrict__ qbf, unsigned short* __restrict__ kbf,
    unsigned short* __restrict__ vT)
{
    __shared__ uint4 As[128][5];
    __shared__ uint4 Bs[64][5];
    const int K = 256;
    int t = threadIdx.x;
    int bm = blockIdx.y * 128, bn = blockIdx.x * 64;
    int grp = bn >> 8, lbn = bn & 255;
    const unsigned short* Bt = (grp == 0) ? Wqt : (grp == 1) ? Wkt : Wvt;
    const float* bias = (grp == 0) ? bq : (grp == 1) ? bk : bv;
    int w = t >> 6, l = t & 63, lm16 = l & 15, quad = l >> 4;
    int ar = t >> 1, ak = (t & 1) * 16;
    int br = t >> 2, bk2 = (t & 3) * 8;
    const unsigned short* Ab = A + (size_t)(bm + ar) * K + ak;
    const unsigned short* Bb = Bt + (size_t)(lbn + br) * K + bk2;
    f32x4 acc[2][4] = {};
    for (int k0 = 0; k0 < K; k0 += 32) {
        uint4 a0 = *(const uint4*)(Ab + k0);
        uint4 a1 = *(const uint4*)(Ab + k0 + 8);
        uint4 b0 = *(const uint4*)(Bb + k0);
        __syncthreads();
        As[ar][(ak >> 3)] = a0; As[ar][(ak >> 3) + 1] = a1;
        Bs[br][bk2 >> 3] = b0;
        __syncthreads();
        bf16x8 af[2], bfr[4];
        af[0] = *(const bf16x8*)&As[w * 32 + lm16][quad];
        af[1] = *(const bf16x8*)&As[w * 32 + 16 + lm16][quad];
#pragma unroll
        for (int j = 0; j < 4; j++) bfr[j] = *(const bf16x8*)&Bs[j * 16 + lm16][quad];
#pragma unroll
        for (int i = 0; i < 2; i++)
#pragma unroll
            for (int j = 0; j < 4; j++)
                acc[i][j] = __builtin_amdgcn_mfma_f32_16x16x32_bf16(af[i], bfr[j], acc[i][j], 0, 0, 0);
    }
#pragma unroll
    for (int i = 0; i < 2; i++)
#pragma unroll
        for (int j = 0; j < 4; j++) {
            int lcol = lbn + j * 16 + lm16;
            float bs = bias[lcol];
            int h = lcol >> 6, e = lcol & 63;
#pragma unroll
            for (int r = 0; r < 4; r++) {
                int row = bm + w * 32 + i * 16 + quad * 4 + r;
                int b = row >> 12, s = row & 4095;
                float v = acc[i][j][r] + bs;
                if (grp == 0)
                    qbf[((size_t)((b << 2) + h) * 4096 + s) * 64 + e] = f2bf(v);
                else if (grp == 1)
                    kbf[((size_t)((b << 2) + h) * 4096 + s) * 64 + e] = f2bf(v);
                else
                    vT[((size_t)((b << 2) + h) * 64 + e) * 4096 + s] = f2bf(v);
            }
        }
}

// ---------------- FFN1 GEMM: gelu(tanh) epilogue, bf16 out ----------------
__global__ __launch_bounds__(256) void ffn1_kernel(
    const unsigned short* __restrict__ A, const unsigned short* __restrict__ Bt,
    const float* __restrict__ bias, unsigned short* __restrict__ Cb, int N, int K)
{
    __shared__ uint4 As[128][5];
    __shared__ uint4 Bs[64][5];
    int t = threadIdx.x;
    int bm = blockIdx.y * 128, bn = blockIdx.x * 64;
    int w = t >> 6, l = t & 63, lm16 = l & 15, quad = l >> 4;
    int ar = t >> 1, ak = (t & 1) * 16;
    int br = t >> 2, bk = (t & 3) * 8;
    const unsigned short* Ab = A + (size_t)(bm + ar) * K + ak;
    const unsigned short* Bb = Bt + (size_t)(bn + br) * K + bk;
    f32x4 acc[2][4] = {};
    for (int k0 = 0; k0 < K; k0 += 32) {
        uint4 a0 = *(const uint4*)(Ab + k0);
        uint4 a1 = *(const uint4*)(Ab + k0 + 8);
        uint4 b0 = *(const uint4*)(Bb + k0);
        __syncthreads();
        As[ar][(ak >> 3)] = a0; As[ar][(ak >> 3) + 1] = a1;
        Bs[br][bk >> 3] = b0;
        __syncthreads();
        bf16x8 af[2], bfr[4];
        af[0] = *(const bf16x8*)&As[w * 32 + lm16][quad];
        af[1] = *(const bf16x8*)&As[w * 32 + 16 + lm16][quad];
#pragma unroll
        for (int j = 0; j < 4; j++) bfr[j] = *(const bf16x8*)&Bs[j * 16 + lm16][quad];
#pragma unroll
        for (int i = 0; i < 2; i++)
#pragma unroll
            for (int j = 0; j < 4; j++)
                acc[i][j] = __builtin_amdgcn_mfma_f32_16x16x32_bf16(af[i], bfr[j], acc[i][j], 0, 0, 0);
    }
#pragma unroll
    for (int i = 0; i < 2; i++)
#pragma unroll
        for (int j = 0; j < 4; j++) {
            int col = bn + j * 16 + lm16;
            float bsv = bias[col];
#pragma unroll
            for (int r = 0; r < 4; r++) {
                int row = bm + w * 32 + i * 16 + quad * 4 + r;
                float v = acc[i][j][r] + bsv;
                float inner = 0.7978845608028654f * (v + 0.044715f * v * v * v);
                float gl = 0.5f * v * (1.0f + tanhf(inner));
                Cb[(size_t)row * N + col] = f2bf(gl);
            }
        }
}

// ---------------- full-row GEMM: 64 rows x N=256 per block ----------------
// EPI 0: +bias +resid(xio); write xio fp32; LayerNorm(lng,lnb) -> outb bf16
// EPI 1: +bias +resid(xio); write xio fp32; plain bf16 cast -> outb
// EPI 2: pooling: alpha[row] = exp(sum_col tanh(v+bias)*p2w + p2b) * mask[row]
template <int EPI>
__global__ __launch_bounds__(256) void gemm_fullrow_kernel(
    const unsigned short* __restrict__ A, const unsigned short* __restrict__ Bt,
    const float* __restrict__ bias, float* __restrict__ xio,
    const float* __restrict__ lng, const float* __restrict__ lnb,
    unsigned short* __restrict__ outb,
    const float* __restrict__ p2w, const float* __restrict__ p2b,
    const float* __restrict__ mask, float* __restrict__ alphab, int K)
{
    __shared__ uint4 As4[64][5];
    __shared__ uint4 Bs4[256][5];
    int t = threadIdx.x;
    int bm = blockIdx.x * 64;
    int w = t >> 6, l = t & 63, lm16 = l & 15, quad = l >> 4;
    int arow = t >> 2, aku = t & 3;
    const unsigned short* Ab = A + (size_t)(bm + arow) * K + aku * 8;
    const unsigned short* Bb = Bt + (size_t)t * K;
    f32x4 acc[16] = {};
    for (int k0 = 0; k0 < K; k0 += 32) {
        uint4 a  = *(const uint4*)(Ab + k0);
        uint4 b0 = *(const uint4*)(Bb + k0);
        uint4 b1 = *(const uint4*)(Bb + k0 + 8);
        uint4 b2 = *(const uint4*)(Bb + k0 + 16);
        uint4 b3 = *(const uint4*)(Bb + k0 + 24);
        __syncthreads();
        As4[arow][aku] = a;
        Bs4[t][0] = b0; Bs4[t][1] = b1; Bs4[t][2] = b2; Bs4[t][3] = b3;
        __syncthreads();
        bf16x8 af = *(const bf16x8*)&As4[w * 16 + lm16][quad];
#pragma unroll
        for (int j = 0; j < 16; j++) {
            bf16x8 bfv = *(const bf16x8*)&Bs4[j * 16 + lm16][quad];
            acc[j] = __builtin_amdgcn_mfma_f32_16x16x32_bf16(af, bfv, acc[j], 0, 0, 0);
        }
    }
    int rbase = bm + w * 16 + quad * 4;
    if (EPI == 2) {
        float rs[4] = {0.f, 0.f, 0.f, 0.f};
#pragma unroll
        for (int j = 0; j < 16; j++) {
            int col = j * 16 + lm16;
            float bs = bias[col], pw = p2w[col];
#pragma unroll
            for (int r = 0; r < 4; r++)
                rs[r] += tanhf(acc[j][r] + bs) * pw;
        }
#pragma unroll
        for (int m2 = 1; m2 <= 8; m2 <<= 1)
#pragma unroll
            for (int r = 0; r < 4; r++) rs[r] += __shfl_xor(rs[r], m2);
        if (lm16 == 0) {
            float pb = p2b[0];
#pragma unroll
            for (int r = 0; r < 4; r++) {
                int row = rbase + r;
                alphab[row] = expf(rs[r] + pb) * mask[row];
            }
        }
        return;
    }
    float rs[4] = {0.f, 0.f, 0.f, 0.f};
#pragma unroll
    for (int j = 0; j < 16; j++) {
        int col = j * 16 + lm16;
        float bs = bias[col];
#pragma unroll
        for (int r = 0; r < 4; r++) {
            float v = acc[j][r] + bs + xio[(size_t)(rbase + r) * 256 + col];
            acc[j][r] = v;
            rs[r] += v;
        }
    }
    float mean[4], rstd[4];
    if (EPI == 0) {
#pragma unroll
        for (int m2 = 1; m2 <= 8; m2 <<= 1)
#pragma unroll
            for (int r = 0; r < 4; r++) rs[r] += __shfl_xor(rs[r], m2);
        float vs[4] = {0.f, 0.f, 0.f, 0.f};
#pragma unroll
        for (int r = 0; r < 4; r++) mean[r] = rs[r] * (1.0f / 256.0f);
#pragma unroll
        for (int j = 0; j < 16; j++)
#pragma unroll
            for (int r = 0; r < 4; r++) {
                float d = acc[j][r] - mean[r];
                vs[r] += d * d;
            }
#pragma unroll
        for (int m2 = 1; m2 <= 8; m2 <<= 1)
#pragma unroll
            for (int r = 0; r < 4; r++) vs[r] += __shfl_xor(vs[r], m2);
#pragma unroll
        for (int r = 0; r < 4; r++) rstd[r] = rsqrtf(vs[r] * (1.0f / 256.0f) + 1e-12f);
    }
#pragma unroll
    for (int j = 0; j < 16; j++) {
        int col = j * 16 + lm16;
        float g  = (EPI == 0) ? lng[col] : 0.f;
        float bb = (EPI == 0) ? lnb[col] : 0.f;
#pragma unroll
        for (int r = 0; r < 4; r++) {
            int row = rbase + r;
            float v = acc[j][r];
            xio[(size_t)row * 256 + col] = v;
            float y = (EPI == 0) ? ((v - mean[r]) * rstd[r] * g + bb) : v;
            outb[(size_t)row * 256 + col] = f2bf(y);
        }
    }
}

// ---------------- k-side phi (tile 128 s x 64 m, K=64) ----------------
// MODE 1: per-block dash max -> pmax. MODE 2: kpT = bf16(RATIO*(exp(dash-stab)+eps)),
//         fused ksum[bh][m] partial via shuffles + atomics.
template <int MODE>
__global__ __launch_bounds__(256) void phi_k_kernel(
    const unsigned short* __restrict__ kbf, const unsigned short* __restrict__ projbf,
    unsigned short* __restrict__ kpT, const float* __restrict__ stab,
    float* __restrict__ pmax, float* __restrict__ ksum)
{
    __shared__ uint4 As[128][9];
    __shared__ uint4 Bs[64][9];
    __shared__ float diag_s[128];
    __shared__ float sred[4];
    __shared__ float ks_w[4][64];
    int t = threadIdx.x;
    int m0 = blockIdx.x * 64;
    int s0 = blockIdx.y * 128;
    int bh = blockIdx.z;
    const unsigned short* src = kbf + ((size_t)bh * 4096 + s0) * 64;
    {
        int row = t >> 1, koff = (t & 1) * 32;
        const uint4* g = (const uint4*)(src + (size_t)row * 64 + koff);
        float ss = 0.f;
#pragma unroll
        for (int i = 0; i < 4; i++) { uint4 u = g[i]; As[row][(koff >> 3) + i] = u; ss += sumsq8(u); }
        ss += __shfl_xor(ss, 1);
        if ((t & 1) == 0) diag_s[row] = DIAGC * ss;
        int brow = t >> 2, bkoff = (t & 3) * 16;
        uint4 zero = {0, 0, 0, 0};
        bool bv = (m0 + brow) < 266;
        const uint4* gp = (const uint4*)(projbf + (size_t)(m0 + brow) * 64 + bkoff);
#pragma unroll
        for (int i = 0; i < 2; i++) Bs[brow][(bkoff >> 3) + i] = bv ? gp[i] : zero;
    }
    __syncthreads();
    int w = t >> 6, l = t & 63, lm16 = l & 15, quad = l >> 4;
    f32x4 acc[2][4] = {};
#pragma unroll
    for (int ks = 0; ks < 2; ks++) {
        bf16x8 af[2], bfr[4];
        af[0] = *(const bf16x8*)&As[w * 32 + lm16][ks * 4 + quad];
        af[1] = *(const bf16x8*)&As[w * 32 + 16 + lm16][ks * 4 + quad];
#pragma unroll
        for (int j = 0; j < 4; j++) bfr[j] = *(const bf16x8*)&Bs[j * 16 + lm16][ks * 4 + quad];
#pragma unroll
        for (int i = 0; i < 2; i++)
#pragma unroll
            for (int j = 0; j < 4; j++)
                acc[i][j] = __builtin_amdgcn_mfma_f32_16x16x32_bf16(af[i], bfr[j], acc[i][j], 0, 0, 0);
    }
    if (MODE == 1) {
        float kmax = -1e30f;
#pragma unroll
        for (int i = 0; i < 2; i++)
#pragma unroll
            for (int j = 0; j < 4; j++)
#pragma unroll
                for (int r = 0; r < 4; r++) {
                    int m = m0 + j * 16 + lm16;
                    if (m >= 266) continue;
                    int srow = w * 32 + i * 16 + quad * 4 + r;
                    kmax = fmaxf(kmax, acc[i][j][r] * DN - diag_s[srow]);
                }
        kmax = wredmax(kmax);
        if (l == 0) sred[w] = kmax;
        __syncthreads();
        if (t == 0)
            pmax[((size_t)bh * 32 + blockIdx.y) * 5 + blockIdx.x] =
                fmaxf(fmaxf(sred[0], sred[1]), fmaxf(sred[2], sred[3]));
    } else {
        float st = stab[0];
        float psum[4] = {0.f, 0.f, 0.f, 0.f};
#pragma unroll
        for (int i = 0; i < 2; i++)
#pragma unroll
            for (int j = 0; j < 4; j++)
#pragma unroll
                for (int r = 0; r < 4; r++) {
                    int m = m0 + j * 16 + lm16;
                    if (m >= 272) continue;
                    int srow = w * 32 + i * 16 + quad * 4 + r;
                    float v = acc[i][j][r] * DN - diag_s[srow];
                    float e = RATIO * (expf(v - st) + FEPS);
                    kpT[((size_t)bh * 272 + m) * 4096 + (s0 + srow)] = f2bf(e);
                    psum[j] += e;
                }
#pragma unroll
        for (int j = 0; j < 4; j++) {
            psum[j] += __shfl_xor(psum[j], 16);
            psum[j] += __shfl_xor(psum[j], 32);
        }
        if (quad == 0) {
#pragma unroll
            for (int j = 0; j < 4; j++) ks_w[w][j * 16 + lm16] = psum[j];
        }
        __syncthreads();
        if (t < 64) {
            int m = m0 + t;
            if (m < 272)
                atomicAdd(&ksum[bh * 272 + m],
                          ks_w[0][t] + ks_w[1][t] + ks_w[2][t] + ks_w[3][t]);
        }
    }
}

__global__ __launch_bounds__(256) void reduce_max_kernel(
    const float* __restrict__ pmax, float* __restrict__ stab, int n)
{
    __shared__ float sred[4];
    int t = threadIdx.x;
    float m = -1e30f;
    for (int i = t; i < n; i += 256) m = fmaxf(m, pmax[i]);
    m = wredmax(m);
    if ((t & 63) == 0) sred[t >> 6] = m;
    __syncthreads();
    if (t == 0) stab[0] = fmaxf(fmaxf(sred[0], sred[1]), fmaxf(sred[2], sred[3]));
}

// ---------------- fused q-side phi: 64 s x 272 m per block ----------------
// dash -> row max -> exp -> qp bf16 [bh][s][272]; denom = qp . ksum -> denomb
__global__ __launch_bounds__(256) void phi_q_fused_kernel(
    const unsigned short* __restrict__ qbf, const unsigned short* __restrict__ projbf,
    const float* __restrict__ ksum, unsigned short* __restrict__ qp,
    float* __restrict__ denomb)
{
    __shared__ uint4 As[64][9];
    __shared__ uint4 Bs[272][9];
    __shared__ float diag_s[64];
    __shared__ float ks_s[272];
    int t = threadIdx.x;
    int s0 = blockIdx.x * 64;
    int bh = blockIdx.y;
    {
        int arow = t >> 2, akoff = (t & 3) * 16;
        const uint4* ga = (const uint4*)(qbf + ((size_t)bh * 4096 + s0 + arow) * 64 + akoff);
        uint4 u0 = ga[0], u1 = ga[1];
        As[arow][(akoff >> 3)] = u0; As[arow][(akoff >> 3) + 1] = u1;
        float ss = sumsq8(u0) + sumsq8(u1);
        ss += __shfl_xor(ss, 1); ss += __shfl_xor(ss, 2);
        if ((t & 3) == 0) diag_s[arow] = DIAGC * ss;
        uint4 zero = {0, 0, 0, 0};
        for (int row = t; row < 272; row += 256) {
            const uint4* gp = (const uint4*)(projbf + (size_t)row * 64);
            bool bv = row < 266;
#pragma unroll
            for (int i2 = 0; i2 < 8; i2++) Bs[row][i2] = bv ? gp[i2] : zero;
        }
        ks_s[t] = ksum[bh * 272 + t];
        if (t < 16) ks_s[256 + t] = ksum[bh * 272 + 256 + t];
    }
    __syncthreads();
    int w = t >> 6, l = t & 63, lm16 = l & 15, quad = l >> 4;
    f32x4 acc[17] = {};
#pragma unroll
    for (int ks = 0; ks < 2; ks++) {
        bf16x8 af = *(const bf16x8*)&As[w * 16 + lm16][ks * 4 + quad];
#pragma unroll
        for (int j = 0; j < 17; j++) {
            bf16x8 bfv = *(const bf16x8*)&Bs[j * 16 + lm16][ks * 4 + quad];
            acc[j] = __builtin_amdgcn_mfma_f32_16x16x32_bf16(af, bfv, acc[j], 0, 0, 0);
        }
    }
    int rloc = w * 16 + quad * 4;
    float dg[4];
#pragma unroll
    for (int r = 0; r < 4; r++) dg[r] = diag_s[rloc + r];
    float vmax[4] = {-1e30f, -1e30f, -1e30f, -1e30f};
#pragma unroll
    for (int j = 0; j < 17; j++) {
        int m = j * 16 + lm16;
        bool valid = m < 266;
#pragma unroll
        for (int r = 0; r < 4; r++) {
            float v = acc[j][r] * DN - dg[r];
            acc[j][r] = v;
            if (valid) vmax[r] = fmaxf(vmax[r], v);
        }
    }
#pragma unroll
    for (int m2 = 1; m2 <= 8; m2 <<= 1)
#pragma unroll
        for (int r = 0; r < 4; r++) vmax[r] = fmaxf(vmax[r], __shfl_xor(vmax[r], m2));
    float den[4] = {0.f, 0.f, 0.f, 0.f};
#pragma unroll
    for (int j = 0; j < 17; j++) {
        int m = j * 16 + lm16;
        bool valid = m < 266;
#pragma unroll
        for (int r = 0; r < 4; r++) {
            float e = valid ? RATIO * (expf(acc[j][r] - vmax[r]) + FEPS) : 0.f;
            qp[((size_t)bh * 4096 + s0 + rloc + r) * 272 + m] = f2bf(e);
            den[r] += e * ks_s[m];
        }
    }
#pragma unroll
    for (int m2 = 1; m2 <= 8; m2 <<= 1)
#pragma unroll
        for (int r = 0; r < 4; r++) den[r] += __shfl_xor(den[r], m2);
    if (lm16 == 0) {
#pragma unroll
        for (int r = 0; r < 4; r++)
            denomb[(size_t)bh * 4096 + s0 + rloc + r] = den[r];
    }
}

// ---------------- ctx MFMA: ctxT[bh][e][m] += sum_s kpT[bh][m][s]*vT[bh][e][s] ----------------
__global__ __launch_bounds__(256) void ctx_mfma_kernel(
    const unsigned short* __restrict__ kpT, const unsigned short* __restrict__ vT,
    float* __restrict__ ctxT)
{
    __shared__ uint4 As[64][9];
    __shared__ uint4 Bs[64][9];
    int t = threadIdx.x;
    int m0 = blockIdx.x * 64;
    int bh = blockIdx.y;
    int sb = blockIdx.z * 1024;
    int w = t >> 6, l = t & 63, lm16 = l & 15, quad = l >> 4;
    int row = t >> 2, koff = (t & 3) * 16;
    bool av = (m0 + row) < 272;
    const uint4* ga = (const uint4*)(kpT + ((size_t)bh * 272 + m0 + row) * 4096 + sb + koff);
    const uint4* gb = (const uint4*)(vT + ((size_t)bh * 64 + row) * 4096 + sb + koff);
    uint4 zero = {0, 0, 0, 0};
    f32x4 acc[4] = {};
    for (int kc = 0; kc < 16; kc++) {
        uint4 a0 = av ? ga[0] : zero, a1 = av ? ga[1] : zero;
        uint4 b0 = gb[0], b1 = gb[1];
        ga += 8; gb += 8;
        __syncthreads();
        As[row][(koff >> 3)] = a0; As[row][(koff >> 3) + 1] = a1;
        Bs[row][(koff >> 3)] = b0; Bs[row][(koff >> 3) + 1] = b1;
        __syncthreads();
#pragma unroll
        for (int ks = 0; ks < 2; ks++) {
            bf16x8 af = *(const bf16x8*)&As[w * 16 + lm16][ks * 4 + quad];
#pragma unroll
            for (int j = 0; j < 4; j++) {
                bf16x8 bfr = *(const bf16x8*)&Bs[j * 16 + lm16][ks * 4 + quad];
                acc[j] = __builtin_amdgcn_mfma_f32_16x16x32_bf16(af, bfr, acc[j], 0, 0, 0);
            }
        }
    }
#pragma unroll
    for (int j = 0; j < 4; j++)
#pragma unroll
        for (int r = 0; r < 4; r++) {
            int m = m0 + w * 16 + quad * 4 + r;
            if (m < 272)
                atomicAdd(&ctxT[((size_t)bh * 64 + j * 16 + lm16) * 272 + m], acc[j][r]);
        }
}

// ---------------- attn MFMA: out = (qp @ ctxT^T)/denom -> abf [b][s][h*64+e] ----------------
__global__ __launch_bounds__(256) void attn_mfma_kernel(
    const unsigned short* __restrict__ qp, const unsigned short* __restrict__ ctxTbf,
    const float* __restrict__ denomb, unsigned short* __restrict__ abf)
{
    __shared__ uint4 As[128][5];
    __shared__ uint4 Bs[64][5];
    int t = threadIdx.x;
    int s0 = blockIdx.x * 128;
    int bh = blockIdx.y; int b = bh >> 2, h = bh & 3;
    int w = t >> 6, l = t & 63, lm16 = l & 15, quad = l >> 4;
    int ar = t >> 1, ak = (t & 1) * 16;
    int br = t >> 2, bk = (t & 3) * 8;
    const unsigned short* Ab = qp + ((size_t)bh * 4096 + s0 + ar) * 272 + ak;
    const unsigned short* Bb = ctxTbf + ((size_t)bh * 64 + br) * 272 + bk;
    uint4 zero = {0, 0, 0, 0};
    f32x4 acc[2][4] = {};
    for (int k0 = 0; k0 < 272; k0 += 32) {
        uint4 a0 = (k0 + ak < 272)     ? *(const uint4*)(Ab + k0)     : zero;
        uint4 a1 = (k0 + ak + 8 < 272) ? *(const uint4*)(Ab + k0 + 8) : zero;
        uint4 b0 = (k0 + bk < 272)     ? *(const uint4*)(Bb + k0)     : zero;
        __syncthreads();
        As[ar][(ak >> 3)] = a0; As[ar][(ak >> 3) + 1] = a1;
        Bs[br][bk >> 3] = b0;
        __syncthreads();
        bf16x8 af[2], bfr[4];
        af[0] = *(const bf16x8*)&As[w * 32 + lm16][quad];
        af[1] = *(const bf16x8*)&As[w * 32 + 16 + lm16][quad];
#pragma unroll
        for (int j = 0; j < 4; j++) bfr[j] = *(const bf16x8*)&Bs[j * 16 + lm16][quad];
#pragma unroll
        for (int i = 0; i < 2; i++)
#pragma unroll
            for (int j = 0; j < 4; j++)
                acc[i][j] = __builtin_amdgcn_mfma_f32_16x16x32_bf16(af[i], bfr[j], acc[i][j], 0, 0, 0);
    }
#pragma unroll
    for (int i = 0; i < 2; i++)
#pragma unroll
        for (int j = 0; j < 4; j++)
#pragma unroll
            for (int r = 0; r < 4; r++) {
                int s = s0 + w * 32 + i * 16 + quad * 4 + r;
                float v = acc[i][j][r] / denomb[(size_t)bh * 4096 + s];
                int e = j * 16 + lm16;
                abf[((size_t)(b * 4096 + s)) * 256 + h * 64 + e] = f2bf(v);
            }
}

// ---------------- pooling tail ----------------
__global__ __launch_bounds__(256) void pool_denom_kernel(
    const float* __restrict__ alpha, float* __restrict__ denomb)
{
    __shared__ float sred[4];
    int b = blockIdx.x, t = threadIdx.x;
    float p = 0.f;
    for (int s = t; s < 4096; s += 256) p += alpha[b * 4096 + s];
    p = wredsum(p);
    if ((t & 63) == 0) sred[t >> 6] = p;
    __syncthreads();
    if (t == 0) denomb[b] = sred[0] + sred[1] + sred[2] + sred[3] + 1e-8f;
}

__global__ __launch_bounds__(256) void pool_out_kernel(
    const float* __restrict__ x, const float* __restrict__ alpha,
    const float* __restrict__ denomb, float* __restrict__ out)
{
    int b = blockIdx.x, chunk = blockIdx.y, t = threadIdx.x;
    float inv = 1.0f / denomb[b];
    float acc = 0.f;
    int s0 = chunk * 128;
    for (int s = s0; s < s0 + 128; s++)
        acc += x[((size_t)(b << 12) + s) * 256 + t] * alpha[(b << 12) + s];
    atomicAdd(&out[b * 256 + t], acc * inv);
}

extern "C" void kernel_launch(void* const* d_in, const int* in_sizes, int n_in,
                              void* d_out, int out_size, void* d_ws, size_t ws_size,
                              hipStream_t stream)
{
    const float* input_embs = (const float*)d_in[0];
    const float* mask  = (const float*)d_in[1];
    const float* pos   = (const float*)d_in[2];
    const float* ln_g  = (const float*)d_in[3];
    const float* ln_b  = (const float*)d_in[4];
    const float* proj  = (const float*)d_in[5];
    const float* Wq = (const float*)d_in[6];  const float* bq = (const float*)d_in[7];
    const float* Wk = (const float*)d_in[8];  const float* bk = (const float*)d_in[9];
    const float* Wv = (const float*)d_in[10]; const float* bv = (const float*)d_in[11];
    const float* Wo = (const float*)d_in[12]; const float* bo = (const float*)d_in[13];
    const float* ln1g = (const float*)d_in[14]; const float* ln1b = (const float*)d_in[15];
    const float* W1 = (const float*)d_in[16]; const float* b1 = (const float*)d_in[17];
    const float* W2 = (const float*)d_in[18]; const float* b2 = (const float*)d_in[19];
    const float* ln2g = (const float*)d_in[20]; const float* ln2b = (const float*)d_in[21];
    const float* p1w = (const float*)d_in[22]; const float* p1b = (const float*)d_in[23];
    const float* p2w = (const float*)d_in[24]; const float* p2b = (const float*)d_in[25];
    float* out = (float*)d_out;
    char* ws = (char*)d_ws;

    size_t off = 0;
    auto alloc = [&](size_t bytes) { size_t o = off; off += WS_ALIGN(bytes); return o; };
    float* xbuf = (float*)(ws + alloc(16384ull * 256 * 4));
    unsigned short* hbf = (unsigned short*)(ws + alloc(16384ull * 256 * 2));   // ln-out / attn-out / x-bf16
    unsigned short* qbf = (unsigned short*)(ws + alloc(16384ull * 256 * 2));
    unsigned short* kbf = (unsigned short*)(ws + alloc(16384ull * 256 * 2));
    unsigned short* vT  = (unsigned short*)(ws + alloc(16384ull * 256 * 2));
    unsigned short* qp  = (unsigned short*)(ws + alloc(16ull * 4096 * 272 * 2)); // alias: FFN mid
    unsigned short* kpT = (unsigned short*)(ws + alloc(16ull * 272 * 4096 * 2));
    size_t ksum_off = alloc(16ull * 272 * 4);
    float* ksum = (float*)(ws + ksum_off);
    float* ctxT = (float*)(ws + alloc(16ull * 64 * 272 * 4));      // adjacent to ksum (one memset)
    size_t zero_bytes = WS_ALIGN(16ull * 272 * 4) + WS_ALIGN(16ull * 64 * 272 * 4);
    unsigned short* ctxTbf = (unsigned short*)(ws + alloc(16ull * 64 * 272 * 2));
    float* denomb = (float*)(ws + alloc(65536ull * 4));
    float* pmaxb = (float*)(ws + alloc(2560ull * 4));
    float* stabb = (float*)(ws + alloc(256));
    float* alphab = (float*)(ws + alloc(16384ull * 4));
    float* pdenom = (float*)(ws + alloc(256));
    unsigned short* Wqt = (unsigned short*)(ws + alloc(4ull * 65536 * 2));
    unsigned short* Wkt = (unsigned short*)(ws + alloc(4ull * 65536 * 2));
    unsigned short* Wvt = (unsigned short*)(ws + alloc(4ull * 65536 * 2));
    unsigned short* Wot = (unsigned short*)(ws + alloc(4ull * 65536 * 2));
    unsigned short* W1t = (unsigned short*)(ws + alloc(4ull * 262144 * 2));
    unsigned short* W2t = (unsigned short*)(ws + alloc(4ull * 262144 * 2));
    unsigned short* projbf = (unsigned short*)(ws + alloc(4ull * 17024 * 2));
    unsigned short* p1t = (unsigned short*)(ws + alloc(65536ull * 2));
    unsigned short* midbf = qp;   // FFN intermediate aliases qp (disjoint lifetimes)
    unsigned short* abf = hbf;
    // total ~133 MB (< 256 MiB)

    // ---- weight casts (all layers up front) ----
    cast_transpose_kernel<<<dim3(8, 8, 4), 256, 0, stream>>>(Wq, Wqt, 256, 256);
    cast_transpose_kernel<<<dim3(8, 8, 4), 256, 0, stream>>>(Wk, Wkt, 256, 256);
    cast_transpose_kernel<<<dim3(8, 8, 4), 256, 0, stream>>>(Wv, Wvt, 256, 256);
    cast_transpose_kernel<<<dim3(8, 8, 4), 256, 0, stream>>>(Wo, Wot, 256, 256);
    cast_transpose_kernel<<<dim3(32, 8, 4), 256, 0, stream>>>(W1, W1t, 256, 1024);
    cast_transpose_kernel<<<dim3(8, 32, 4), 256, 0, stream>>>(W2, W2t, 1024, 256);
    cast_transpose_kernel<<<dim3(8, 8, 1), 256, 0, stream>>>(p1w, p1t, 256, 256);
    cast_row_kernel<<<67, 256, 0, stream>>>((const float4*)proj, (ushort4*)projbf, 17024);

    // ---- x = LN(input + pos); hbf = LN1_0(x) ----
    add_ln_kernel<false><<<16384, 256, 0, stream>>>(input_embs, pos, ln_g, ln_b, xbuf, nullptr);
    add_ln_kernel<true><<<16384, 256, 0, stream>>>(xbuf, nullptr, ln1g, ln1b, nullptr, hbf);

    for (int i = 0; i < 4; i++) {
        const unsigned short* pj = projbf + (size_t)i * 17024;
        // QKV fused
        qkv_kernel<<<dim3(12, 128), 256, 0, stream>>>(hbf,
            Wqt + (size_t)i * 65536, Wkt + (size_t)i * 65536, Wvt + (size_t)i * 65536,
            bq + i * 256, bk + i * 256, bv + i * 256, qbf, kbf, vT);
        // k-side: max pass, stabilizer, exp pass with fused ksum
        phi_k_kernel<1><<<dim3(5, 32, 16), 256, 0, stream>>>(kbf, pj, nullptr, nullptr, pmaxb, nullptr);
        reduce_max_kernel<<<1, 256, 0, stream>>>(pmaxb, stabb, 2560);
        hipMemsetAsync(ws + ksum_off, 0, zero_bytes, stream);
        phi_k_kernel<2><<<dim3(5, 32, 16), 256, 0, stream>>>(kbf, pj, kpT, stabb, nullptr, ksum);
        // q-side fully fused (dash + rowmax + exp + denom)
        phi_q_fused_kernel<<<dim3(64, 16), 256, 0, stream>>>(qbf, pj, ksum, qp, denomb);
        // ctx + attn out
        ctx_mfma_kernel<<<dim3(5, 16, 4), 256, 0, stream>>>(kpT, vT, ctxT);
        cast_row_kernel<<<272, 256, 0, stream>>>((const float4*)ctxT, (ushort4*)ctxTbf, 16 * 64 * 272 / 4);
        attn_mfma_kernel<<<dim3(32, 16), 256, 0, stream>>>(qp, ctxTbf, denomb, abf);
        // Wo + residual + LN2 fused
        gemm_fullrow_kernel<0><<<256, 256, 0, stream>>>(abf, Wot + (size_t)i * 65536,
            bo + i * 256, xbuf, ln2g + i * 256, ln2b + i * 256, hbf,
            nullptr, nullptr, nullptr, nullptr, 256);
        // FFN
        ffn1_kernel<<<dim3(16, 128), 256, 0, stream>>>(hbf, W1t + (size_t)i * 262144,
            b1 + i * 1024, midbf, 1024, 256);
        if (i < 3)
            gemm_fullrow_kernel<0><<<256, 256, 0, stream>>>(midbf, W2t + (size_t)i * 262144,
                b2 + i * 256, xbuf, ln1g + (i + 1) * 256, ln1b + (i + 1) * 256, hbf,
                nullptr, nullptr, nullptr, nullptr, 1024);
        else
            gemm_fullrow_kernel<1><<<256, 256, 0, stream>>>(midbf, W2t + (size_t)i * 262144,
                b2 + i * 256, xbuf, nullptr, nullptr, hbf,
                nullptr, nullptr, nullptr, nullptr, 1024);
    }

    // ---- attention pooling (score fused into GEMM) ----
    gemm_fullrow_kernel<2><<<256, 256, 0, stream>>>(hbf, p1t, p1b, nullptr, nullptr, nullptr,
        nullptr, p2w, p2b, mask, alphab, 256);
    pool_denom_kernel<<<4, 256, 0, stream>>>(alphab, pdenom);
    hipMemsetAsync(d_out, 0, (size_t)out_size * sizeof(float), stream);
    pool_out_kernel<<<dim3(4, 32), 256, 0, stream>>>(xbuf, alphab, pdenom, out);
}

// Round 6
// 989.498 us; speedup vs baseline: 8.8963x; 1.1772x over previous
//
#include <hip/hip_runtime.h>
#include <math.h>

// Performer encoder on MI355X: B=4, S=4096, D=256, H=4, DH=64, L=4, M=266.
// bf16 MFMA everywhere; fp32 residual stream / LN stats / softmax logic.
// Round 6: kpT eliminated — k-exp + ksum + ctx fused into one flash-style kernel
// (dash MFMA -> exp -> LDS C->A layout transform -> ctx MFMA). k-max pass moved to
// the 64s x 272m "row" tiling shared with the q-side. Workspace ~95 MB.

#define WS_ALIGN(x) (((x) + 255) & ~(size_t)255)

#define DN 0.35355339059327373f      // 64^-0.25
#define DIAGC 0.0625f                 // 0.5 * 64^-0.5
#define RATIO 0.06131393394849658f    // 266^-0.5
#define FEPS 1e-4f

typedef __attribute__((__ext_vector_type__(8))) __bf16 bf16x8;
typedef __attribute__((__ext_vector_type__(4))) float f32x4;

__device__ __forceinline__ float wredsum(float v) {
    v += __shfl_xor(v, 32); v += __shfl_xor(v, 16); v += __shfl_xor(v, 8);
    v += __shfl_xor(v, 4);  v += __shfl_xor(v, 2);  v += __shfl_xor(v, 1);
    return v;
}
__device__ __forceinline__ float wredmax(float v) {
    v = fmaxf(v, __shfl_xor(v, 32)); v = fmaxf(v, __shfl_xor(v, 16));
    v = fmaxf(v, __shfl_xor(v, 8));  v = fmaxf(v, __shfl_xor(v, 4));
    v = fmaxf(v, __shfl_xor(v, 2));  v = fmaxf(v, __shfl_xor(v, 1));
    return v;
}

__device__ __forceinline__ unsigned short f2bf(float f) {
    unsigned u = __builtin_bit_cast(unsigned, f);
    return (unsigned short)((u + 0x7fffu + ((u >> 16) & 1u)) >> 16);
}
__device__ __forceinline__ float blo(unsigned x) { return __builtin_bit_cast(float, x << 16); }
__device__ __forceinline__ float bhi(unsigned x) { return __builtin_bit_cast(float, x & 0xffff0000u); }
__device__ __forceinline__ float sumsq8(uint4 u) {
    float s = 0.f;
    s += blo(u.x)*blo(u.x) + bhi(u.x)*bhi(u.x);
    s += blo(u.y)*blo(u.y) + bhi(u.y)*bhi(u.y);
    s += blo(u.z)*blo(u.z) + bhi(u.z)*bhi(u.z);
    s += blo(u.w)*blo(u.w) + bhi(u.w)*bhi(u.w);
    return s;
}

// ---------------- LayerNorm (fp32 in, fp32 or bf16 out) ----------------
template <bool OBF>
__global__ __launch_bounds__(256) void add_ln_kernel(
    const float* __restrict__ in, const float* __restrict__ pos,
    const float* __restrict__ g, const float* __restrict__ bta,
    float* __restrict__ outf, unsigned short* __restrict__ outb)
{
    int row = blockIdx.x, t = threadIdx.x;
    __shared__ float sred[4];
    float v = in[(size_t)row * 256 + t];
    if (pos) v += pos[(size_t)(row & 4095) * 256 + t];
    float s = wredsum(v);
    if ((t & 63) == 0) sred[t >> 6] = s;
    __syncthreads();
    float mean = (sred[0] + sred[1] + sred[2] + sred[3]) * (1.0f / 256.0f);
    float d = v - mean;
    __syncthreads();
    float sq = wredsum(d * d);
    if ((t & 63) == 0) sred[t >> 6] = sq;
    __syncthreads();
    float var = (sred[0] + sred[1] + sred[2] + sred[3]) * (1.0f / 256.0f);
    float y = d * rsqrtf(var + 1e-12f) * g[t] + bta[t];
    if (OBF) outb[(size_t)row * 256 + t] = f2bf(y);
    else     outf[(size_t)row * 256 + t] = y;
}

// ---------------- weight cast/transpose: fp32 [R][C] -> bf16 [C][R] ----------------
__global__ __launch_bounds__(256) void cast_transpose_kernel(
    const float* __restrict__ in, unsigned short* __restrict__ out, int R, int C)
{
    __shared__ float tile[32][33];
    size_t zo = (size_t)blockIdx.z * R * C;
    int c0 = blockIdx.x * 32, r0 = blockIdx.y * 32;
    int t = threadIdx.x, tc = t & 31, tr = t >> 5;
#pragma unroll
    for (int j = 0; j < 4; j++)
        tile[tr + j * 8][tc] = in[zo + (size_t)(r0 + tr + j * 8) * C + c0 + tc];
    __syncthreads();
#pragma unroll
    for (int j = 0; j < 4; j++) {
        int cc = tr + j * 8, rr = tc;
        out[zo + (size_t)(c0 + cc) * R + r0 + rr] = f2bf(tile[rr][cc]);
    }
}

// fp32 -> bf16 elementwise (n4 = count/4)
__global__ __launch_bounds__(256) void cast_row_kernel(
    const float4* __restrict__ in, ushort4* __restrict__ out, int n4)
{
    int i = blockIdx.x * 256 + threadIdx.x;
    if (i >= n4) return;
    float4 v = in[i];
    ushort4 o; o.x = f2bf(v.x); o.y = f2bf(v.y); o.z = f2bf(v.z); o.w = f2bf(v.w);
    out[i] = o;
}

// ---------------- fused QKV GEMM (N=768 over q|k|v), K=256 ----------------
__global__ __launch_bounds__(256) void qkv_kernel(
    const unsigned short* __restrict__ A,
    const unsigned short* __restrict__ Wqt, const unsigned short* __restrict__ Wkt,
    const unsigned short* __restrict__ Wvt,
    const float* __restrict__ bq, const float* __restrict__ bk, const float* __restrict__ bv,
    unsigned short* __restrict__ qbf, unsigned short* __restrict__ kbf,
    unsigned short* __restrict__ vT)
{
    __shared__ uint4 As[128][5];
    __shared__ uint4 Bs[64][5];
    const int K = 256;
    int t = threadIdx.x;
    int bm = blockIdx.y * 128, bn = blockIdx.x * 64;
    int grp = bn >> 8, lbn = bn & 255;
    const unsigned short* Bt = (grp == 0) ? Wqt : (grp == 1) ? Wkt : Wvt;
    const float* bias = (grp == 0) ? bq : (grp == 1) ? bk : bv;
    int w = t >> 6, l = t & 63, lm16 = l & 15, quad = l >> 4;
    int ar = t >> 1, ak = (t & 1) * 16;
    int br = t >> 2, bk2 = (t & 3) * 8;
    const unsigned short* Ab = A + (size_t)(bm + ar) * K + ak;
    const unsigned short* Bb = Bt + (size_t)(lbn + br) * K + bk2;
    f32x4 acc[2][4] = {};
    for (int k0 = 0; k0 < K; k0 += 32) {
        uint4 a0 = *(const uint4*)(Ab + k0);
        uint4 a1 = *(const uint4*)(Ab + k0 + 8);
        uint4 b0 = *(const uint4*)(Bb + k0);
        __syncthreads();
        As[ar][(ak >> 3)] = a0; As[ar][(ak >> 3) + 1] = a1;
        Bs[br][bk2 >> 3] = b0;
        __syncthreads();
        bf16x8 af[2], bfr[4];
        af[0] = *(const bf16x8*)&As[w * 32 + lm16][quad];
        af[1] = *(const bf16x8*)&As[w * 32 + 16 + lm16][quad];
#pragma unroll
        for (int j = 0; j < 4; j++) bfr[j] = *(const bf16x8*)&Bs[j * 16 + lm16][quad];
#pragma unroll
        for (int i = 0; i < 2; i++)
#pragma unroll
            for (int j = 0; j < 4; j++)
                acc[i][j] = __builtin_amdgcn_mfma_f32_16x16x32_bf16(af[i], bfr[j], acc[i][j], 0, 0, 0);
    }
#pragma unroll
    for (int i = 0; i < 2; i++)
#pragma unroll
        for (int j = 0; j < 4; j++) {
            int lcol = lbn + j * 16 + lm16;
            float bs = bias[lcol];
            int h = lcol >> 6, e = lcol & 63;
#pragma unroll
            for (int r = 0; r < 4; r++) {
                int row = bm + w * 32 + i * 16 + quad * 4 + r;
                int b = row >> 12, s = row & 4095;
                float v = acc[i][j][r] + bs;
                if (grp == 0)
                    qbf[((size_t)((b << 2) + h) * 4096 + s) * 64 + e] = f2bf(v);
                else if (grp == 1)
                    kbf[((size_t)((b << 2) + h) * 4096 + s) * 64 + e] = f2bf(v);
                else
                    vT[((size_t)((b << 2) + h) * 64 + e) * 4096 + s] = f2bf(v);
            }
        }
}

// ---------------- FFN1 GEMM: gelu(tanh) epilogue, bf16 out ----------------
__global__ __launch_bounds__(256) void ffn1_kernel(
    const unsigned short* __restrict__ A, const unsigned short* __restrict__ Bt,
    const float* __restrict__ bias, unsigned short* __restrict__ Cb, int N, int K)
{
    __shared__ uint4 As[128][5];
    __shared__ uint4 Bs[64][5];
    int t = threadIdx.x;
    int bm = blockIdx.y * 128, bn = blockIdx.x * 64;
    int w = t >> 6, l = t & 63, lm16 = l & 15, quad = l >> 4;
    int ar = t >> 1, ak = (t & 1) * 16;
    int br = t >> 2, bk = (t & 3) * 8;
    const unsigned short* Ab = A + (size_t)(bm + ar) * K + ak;
    const unsigned short* Bb = Bt + (size_t)(bn + br) * K + bk;
    f32x4 acc[2][4] = {};
    for (int k0 = 0; k0 < K; k0 += 32) {
        uint4 a0 = *(const uint4*)(Ab + k0);
        uint4 a1 = *(const uint4*)(Ab + k0 + 8);
        uint4 b0 = *(const uint4*)(Bb + k0);
        __syncthreads();
        As[ar][(ak >> 3)] = a0; As[ar][(ak >> 3) + 1] = a1;
        Bs[br][bk >> 3] = b0;
        __syncthreads();
        bf16x8 af[2], bfr[4];
        af[0] = *(const bf16x8*)&As[w * 32 + lm16][quad];
        af[1] = *(const bf16x8*)&As[w * 32 + 16 + lm16][quad];
#pragma unroll
        for (int j = 0; j < 4; j++) bfr[j] = *(const bf16x8*)&Bs[j * 16 + lm16][quad];
#pragma unroll
        for (int i = 0; i < 2; i++)
#pragma unroll
            for (int j = 0; j < 4; j++)
                acc[i][j] = __builtin_amdgcn_mfma_f32_16x16x32_bf16(af[i], bfr[j], acc[i][j], 0, 0, 0);
    }
#pragma unroll
    for (int i = 0; i < 2; i++)
#pragma unroll
        for (int j = 0; j < 4; j++) {
            int col = bn + j * 16 + lm16;
            float bsv = bias[col];
#pragma unroll
            for (int r = 0; r < 4; r++) {
                int row = bm + w * 32 + i * 16 + quad * 4 + r;
                float v = acc[i][j][r] + bsv;
                float inner = 0.7978845608028654f * (v + 0.044715f * v * v * v);
                float gl = 0.5f * v * (1.0f + tanhf(inner));
                Cb[(size_t)row * N + col] = f2bf(gl);
            }
        }
}

// ---------------- full-row GEMM: 64 rows x N=256 per block ----------------
// EPI 0: +bias +resid(xio); write xio fp32; LayerNorm -> outb bf16
// EPI 1: +bias +resid(xio); write xio fp32; plain bf16 cast -> outb
// EPI 2: pooling: alpha[row] = exp(sum_col tanh(v+bias)*p2w + p2b) * mask[row]
template <int EPI>
__global__ __launch_bounds__(256) void gemm_fullrow_kernel(
    const unsigned short* __restrict__ A, const unsigned short* __restrict__ Bt,
    const float* __restrict__ bias, float* __restrict__ xio,
    const float* __restrict__ lng, const float* __restrict__ lnb,
    unsigned short* __restrict__ outb,
    const float* __restrict__ p2w, const float* __restrict__ p2b,
    const float* __restrict__ mask, float* __restrict__ alphab, int K)
{
    __shared__ uint4 As4[64][5];
    __shared__ uint4 Bs4[256][5];
    int t = threadIdx.x;
    int bm = blockIdx.x * 64;
    int w = t >> 6, l = t & 63, lm16 = l & 15, quad = l >> 4;
    int arow = t >> 2, aku = t & 3;
    const unsigned short* Ab = A + (size_t)(bm + arow) * K + aku * 8;
    const unsigned short* Bb = Bt + (size_t)t * K;
    f32x4 acc[16] = {};
    for (int k0 = 0; k0 < K; k0 += 32) {
        uint4 a  = *(const uint4*)(Ab + k0);
        uint4 b0 = *(const uint4*)(Bb + k0);
        uint4 b1 = *(const uint4*)(Bb + k0 + 8);
        uint4 b2 = *(const uint4*)(Bb + k0 + 16);
        uint4 b3 = *(const uint4*)(Bb + k0 + 24);
        __syncthreads();
        As4[arow][aku] = a;
        Bs4[t][0] = b0; Bs4[t][1] = b1; Bs4[t][2] = b2; Bs4[t][3] = b3;
        __syncthreads();
        bf16x8 af = *(const bf16x8*)&As4[w * 16 + lm16][quad];
#pragma unroll
        for (int j = 0; j < 16; j++) {
            bf16x8 bfv = *(const bf16x8*)&Bs4[j * 16 + lm16][quad];
            acc[j] = __builtin_amdgcn_mfma_f32_16x16x32_bf16(af, bfv, acc[j], 0, 0, 0);
        }
    }
    int rbase = bm + w * 16 + quad * 4;
    if (EPI == 2) {
        float rs[4] = {0.f, 0.f, 0.f, 0.f};
#pragma unroll
        for (int j = 0; j < 16; j++) {
            int col = j * 16 + lm16;
            float bs = bias[col], pw = p2w[col];
#pragma unroll
            for (int r = 0; r < 4; r++)
                rs[r] += tanhf(acc[j][r] + bs) * pw;
        }
#pragma unroll
        for (int m2 = 1; m2 <= 8; m2 <<= 1)
#pragma unroll
            for (int r = 0; r < 4; r++) rs[r] += __shfl_xor(rs[r], m2);
        if (lm16 == 0) {
            float pb = p2b[0];
#pragma unroll
            for (int r = 0; r < 4; r++) {
                int row = rbase + r;
                alphab[row] = expf(rs[r] + pb) * mask[row];
            }
        }
        return;
    }
    float rs[4] = {0.f, 0.f, 0.f, 0.f};
#pragma unroll
    for (int j = 0; j < 16; j++) {
        int col = j * 16 + lm16;
        float bs = bias[col];
#pragma unroll
        for (int r = 0; r < 4; r++) {
            float v = acc[j][r] + bs + xio[(size_t)(rbase + r) * 256 + col];
            acc[j][r] = v;
            rs[r] += v;
        }
    }
    float mean[4], rstd[4];
    if (EPI == 0) {
#pragma unroll
        for (int m2 = 1; m2 <= 8; m2 <<= 1)
#pragma unroll
            for (int r = 0; r < 4; r++) rs[r] += __shfl_xor(rs[r], m2);
        float vs[4] = {0.f, 0.f, 0.f, 0.f};
#pragma unroll
        for (int r = 0; r < 4; r++) mean[r] = rs[r] * (1.0f / 256.0f);
#pragma unroll
        for (int j = 0; j < 16; j++)
#pragma unroll
            for (int r = 0; r < 4; r++) {
                float d = acc[j][r] - mean[r];
                vs[r] += d * d;
            }
#pragma unroll
        for (int m2 = 1; m2 <= 8; m2 <<= 1)
#pragma unroll
            for (int r = 0; r < 4; r++) vs[r] += __shfl_xor(vs[r], m2);
#pragma unroll
        for (int r = 0; r < 4; r++) rstd[r] = rsqrtf(vs[r] * (1.0f / 256.0f) + 1e-12f);
    }
#pragma unroll
    for (int j = 0; j < 16; j++) {
        int col = j * 16 + lm16;
        float g  = (EPI == 0) ? lng[col] : 0.f;
        float bb = (EPI == 0) ? lnb[col] : 0.f;
#pragma unroll
        for (int r = 0; r < 4; r++) {
            int row = rbase + r;
            float v = acc[j][r];
            xio[(size_t)row * 256 + col] = v;
            float y = (EPI == 0) ? ((v - mean[r]) * rstd[r] * g + bb) : v;
            outb[(size_t)row * 256 + col] = f2bf(y);
        }
    }
}

// ---------------- phi row kernel: 64 s x 272 m per block ----------------
// MODE 0 (q): dash -> row max -> exp -> qp bf16 [bh][s][272]; denom = qp.ksum
// MODE 1 (k): dash -> block max -> pmax[bh*64 + blk]
template <int MODE>
__global__ __launch_bounds__(256) void phi_row_kernel(
    const unsigned short* __restrict__ xbf, const unsigned short* __restrict__ projbf,
    const float* __restrict__ ksum, unsigned short* __restrict__ qp,
    float* __restrict__ denomb, float* __restrict__ pmax)
{
    __shared__ uint4 As[64][9];
    __shared__ uint4 Bs[272][9];
    __shared__ float diag_s[64];
    __shared__ float ks_s[272];
    __shared__ float sred[4];
    int t = threadIdx.x;
    int s0 = blockIdx.x * 64;
    int bh = blockIdx.y;
    {
        int arow = t >> 2, akoff = (t & 3) * 16;
        const uint4* ga = (const uint4*)(xbf + ((size_t)bh * 4096 + s0 + arow) * 64 + akoff);
        uint4 u0 = ga[0], u1 = ga[1];
        As[arow][(akoff >> 3)] = u0; As[arow][(akoff >> 3) + 1] = u1;
        float ss = sumsq8(u0) + sumsq8(u1);
        ss += __shfl_xor(ss, 1); ss += __shfl_xor(ss, 2);
        if ((t & 3) == 0) diag_s[arow] = DIAGC * ss;
        uint4 zero = {0, 0, 0, 0};
        for (int row = t; row < 272; row += 256) {
            const uint4* gp = (const uint4*)(projbf + (size_t)row * 64);
            bool bv = row < 266;
#pragma unroll
            for (int i2 = 0; i2 < 8; i2++) Bs[row][i2] = bv ? gp[i2] : zero;
        }
        if (MODE == 0) {
            ks_s[t] = ksum[bh * 272 + t];
            if (t < 16) ks_s[256 + t] = ksum[bh * 272 + 256 + t];
        }
    }
    __syncthreads();
    int w = t >> 6, l = t & 63, lm16 = l & 15, quad = l >> 4;
    f32x4 acc[17] = {};
#pragma unroll
    for (int ks = 0; ks < 2; ks++) {
        bf16x8 af = *(const bf16x8*)&As[w * 16 + lm16][ks * 4 + quad];
#pragma unroll
        for (int j = 0; j < 17; j++) {
            bf16x8 bfv = *(const bf16x8*)&Bs[j * 16 + lm16][ks * 4 + quad];
            acc[j] = __builtin_amdgcn_mfma_f32_16x16x32_bf16(af, bfv, acc[j], 0, 0, 0);
        }
    }
    int rloc = w * 16 + quad * 4;
    float dg[4];
#pragma unroll
    for (int r = 0; r < 4; r++) dg[r] = diag_s[rloc + r];
    if (MODE == 1) {
        float kmax = -1e30f;
#pragma unroll
        for (int j = 0; j < 17; j++) {
            int m = j * 16 + lm16;
            bool valid = m < 266;
#pragma unroll
            for (int r = 0; r < 4; r++)
                if (valid) kmax = fmaxf(kmax, acc[j][r] * DN - dg[r]);
        }
        kmax = wredmax(kmax);
        if (l == 0) sred[w] = kmax;
        __syncthreads();
        if (t == 0)
            pmax[(size_t)bh * 64 + blockIdx.x] =
                fmaxf(fmaxf(sred[0], sred[1]), fmaxf(sred[2], sred[3]));
        return;
    }
    float vmax[4] = {-1e30f, -1e30f, -1e30f, -1e30f};
#pragma unroll
    for (int j = 0; j < 17; j++) {
        int m = j * 16 + lm16;
        bool valid = m < 266;
#pragma unroll
        for (int r = 0; r < 4; r++) {
            float v = acc[j][r] * DN - dg[r];
            acc[j][r] = v;
            if (valid) vmax[r] = fmaxf(vmax[r], v);
        }
    }
#pragma unroll
    for (int m2 = 1; m2 <= 8; m2 <<= 1)
#pragma unroll
        for (int r = 0; r < 4; r++) vmax[r] = fmaxf(vmax[r], __shfl_xor(vmax[r], m2));
    float den[4] = {0.f, 0.f, 0.f, 0.f};
#pragma unroll
    for (int j = 0; j < 17; j++) {
        int m = j * 16 + lm16;
        bool valid = m < 266;
#pragma unroll
        for (int r = 0; r < 4; r++) {
            float e = valid ? RATIO * (expf(acc[j][r] - vmax[r]) + FEPS) : 0.f;
            qp[((size_t)bh * 4096 + s0 + rloc + r) * 272 + m] = f2bf(e);
            den[r] += e * ks_s[m];
        }
    }
#pragma unroll
    for (int m2 = 1; m2 <= 8; m2 <<= 1)
#pragma unroll
        for (int r = 0; r < 4; r++) den[r] += __shfl_xor(den[r], m2);
    if (lm16 == 0) {
#pragma unroll
        for (int r = 0; r < 4; r++)
            denomb[(size_t)bh * 4096 + s0 + rloc + r] = den[r];
    }
}

__global__ __launch_bounds__(256) void reduce_max_kernel(
    const float* __restrict__ pmax, float* __restrict__ stab, int n)
{
    __shared__ float sred[4];
    int t = threadIdx.x;
    float m = -1e30f;
    for (int i = t; i < n; i += 256) m = fmaxf(m, pmax[i]);
    m = wredmax(m);
    if ((t & 63) == 0) sred[t >> 6] = m;
    __syncthreads();
    if (t == 0) stab[0] = fmaxf(fmaxf(sred[0], sred[1]), fmaxf(sred[2], sred[3]));
}

// ---------------- fused ctx: dash -> exp -> (LDS transform) -> ctx MFMA + ksum ----------------
// Per block (m0, bh, sb): ctxT[bh][e][m0..+64] += sum_{s in slab} kp[m][s]*vT[e][s],
// kp computed in-register from kbf/proj; ksum[bh][m] atomically accumulated.
__global__ __launch_bounds__(256) void ctx_fused_kernel(
    const unsigned short* __restrict__ kbf, const unsigned short* __restrict__ vT,
    const unsigned short* __restrict__ projbf, const float* __restrict__ stab,
    float* __restrict__ ksum, float* __restrict__ ctxT)
{
    __shared__ uint4 Ap[64][9];               // proj tile [m_loc][k]
    __shared__ uint4 Ks[64][9];               // k chunk   [s_loc][k]
    __shared__ uint4 Vs[64][9];               // v chunk   [e][s_loc]
    __shared__ unsigned short kp_s[64][72];   // kp tile   [m_loc][s_loc] (pad 72: 16B-aligned rows)
    __shared__ float diag_s[64];
    int t = threadIdx.x;
    int m0 = blockIdx.x * 64;
    int bh = blockIdx.y;
    int sb = blockIdx.z * 512;
    int w = t >> 6, l = t & 63, lm16 = l & 15, quad = l >> 4;
    {   // stage proj tile once (zero m >= 266)
        int row = t >> 2, koff = (t & 3) * 16;
        uint4 zero = {0, 0, 0, 0};
        bool bv = (m0 + row) < 266;
        const uint4* gp = (const uint4*)(projbf + (size_t)(m0 + row) * 64 + koff);
        Ap[row][(koff >> 3)] = bv ? gp[0] : zero;
        Ap[row][(koff >> 3) + 1] = bv ? gp[1] : zero;
    }
    float st = stab[0];
    f32x4 accc[4] = {};                        // ctx acc: e = w*16 block x 4 m-tiles
    float ksacc[4] = {0.f, 0.f, 0.f, 0.f};     // per-lane ksum partials (m = m0+w*16+quad*4+r)
    int srow = t >> 2, skoff = (t & 3) * 16;
    for (int kc = 0; kc < 8; kc++) {
        int sc = sb + kc * 64;
        const uint4* gk = (const uint4*)(kbf + ((size_t)bh * 4096 + sc + srow) * 64 + skoff);
        uint4 k0 = gk[0], k1 = gk[1];
        const uint4* gv = (const uint4*)(vT + ((size_t)bh * 64 + srow) * 4096 + sc + skoff);
        uint4 v0 = gv[0], v1 = gv[1];
        __syncthreads();
        Ks[srow][(skoff >> 3)] = k0; Ks[srow][(skoff >> 3) + 1] = k1;
        Vs[srow][(skoff >> 3)] = v0; Vs[srow][(skoff >> 3) + 1] = v1;
        float ss = sumsq8(k0) + sumsq8(k1);
        ss += __shfl_xor(ss, 1); ss += __shfl_xor(ss, 2);
        if ((t & 3) == 0) diag_s[srow] = DIAGC * ss;
        __syncthreads();
        // dash MFMA: D[m][s], wave w covers m-rows w*16..+15
        f32x4 accd[4] = {};
#pragma unroll
        for (int ks = 0; ks < 2; ks++) {
            bf16x8 af = *(const bf16x8*)&Ap[w * 16 + lm16][ks * 4 + quad];
#pragma unroll
            for (int j = 0; j < 4; j++) {
                bf16x8 bfv = *(const bf16x8*)&Ks[j * 16 + lm16][ks * 4 + quad];
                accd[j] = __builtin_amdgcn_mfma_f32_16x16x32_bf16(af, bfv, accd[j], 0, 0, 0);
            }
        }
        // epilogue: exp -> kp_s (C-layout positions), ksum partials in regs
        int mbase = m0 + w * 16 + quad * 4;
#pragma unroll
        for (int j = 0; j < 4; j++) {
            int s_loc = j * 16 + lm16;
            float dgv = diag_s[s_loc];
#pragma unroll
            for (int r = 0; r < 4; r++) {
                float v = accd[j][r] * DN - dgv;
                float e = (mbase + r < 266) ? RATIO * (expf(v - st) + FEPS) : 0.f;
                kp_s[w * 16 + quad * 4 + r][s_loc] = f2bf(e);
                ksacc[r] += e;
            }
        }
        __syncthreads();
        // ctx MFMA: D[e][m] += vT[e][s]*kp[m][s]; wave w covers e-rows w*16..+15
#pragma unroll
        for (int ks = 0; ks < 2; ks++) {
            bf16x8 af = *(const bf16x8*)&Vs[w * 16 + lm16][ks * 4 + quad];
#pragma unroll
            for (int jt = 0; jt < 4; jt++) {
                bf16x8 bfv = *(const bf16x8*)&kp_s[jt * 16 + lm16][ks * 32 + quad * 8];
                accc[jt] = __builtin_amdgcn_mfma_f32_16x16x32_bf16(af, bfv, accc[jt], 0, 0, 0);
            }
        }
    }
    // ksum: reduce per-lane partials over the 16 lanes sharing m, one atomic per m
#pragma unroll
    for (int r = 0; r < 4; r++) {
        float v = ksacc[r];
        v += __shfl_xor(v, 1); v += __shfl_xor(v, 2);
        v += __shfl_xor(v, 4); v += __shfl_xor(v, 8);
        if (lm16 == 0) {
            int m = m0 + w * 16 + quad * 4 + r;
            if (m < 272) atomicAdd(&ksum[bh * 272 + m], v);
        }
    }
    // ctxT writes (C-layout: e = w*16+quad*4+r, m = m0+jt*16+lm16)
#pragma unroll
    for (int jt = 0; jt < 4; jt++) {
        int m = m0 + jt * 16 + lm16;
        if (m >= 272) continue;
#pragma unroll
        for (int r = 0; r < 4; r++) {
            int e = w * 16 + quad * 4 + r;
            atomicAdd(&ctxT[((size_t)bh * 64 + e) * 272 + m], accc[jt][r]);
        }
    }
}

// ---------------- attn MFMA: out = (qp @ ctxT^T)/denom -> abf [b][s][h*64+e] ----------------
__global__ __launch_bounds__(256) void attn_mfma_kernel(
    const unsigned short* __restrict__ qp, const unsigned short* __restrict__ ctxTbf,
    const float* __restrict__ denomb, unsigned short* __restrict__ abf)
{
    __shared__ uint4 As[128][5];
    __shared__ uint4 Bs[64][5];
    int t = threadIdx.x;
    int s0 = blockIdx.x * 128;
    int bh = blockIdx.y; int b = bh >> 2, h = bh & 3;
    int w = t >> 6, l = t & 63, lm16 = l & 15, quad = l >> 4;
    int ar = t >> 1, ak = (t & 1) * 16;
    int br = t >> 2, bk = (t & 3) * 8;
    const unsigned short* Ab = qp + ((size_t)bh * 4096 + s0 + ar) * 272 + ak;
    const unsigned short* Bb = ctxTbf + ((size_t)bh * 64 + br) * 272 + bk;
    uint4 zero = {0, 0, 0, 0};
    f32x4 acc[2][4] = {};
    for (int k0 = 0; k0 < 272; k0 += 32) {
        uint4 a0 = (k0 + ak < 272)     ? *(const uint4*)(Ab + k0)     : zero;
        uint4 a1 = (k0 + ak + 8 < 272) ? *(const uint4*)(Ab + k0 + 8) : zero;
        uint4 b0 = (k0 + bk < 272)     ? *(const uint4*)(Bb + k0)     : zero;
        __syncthreads();
        As[ar][(ak >> 3)] = a0; As[ar][(ak >> 3) + 1] = a1;
        Bs[br][bk >> 3] = b0;
        __syncthreads();
        bf16x8 af[2], bfr[4];
        af[0] = *(const bf16x8*)&As[w * 32 + lm16][quad];
        af[1] = *(const bf16x8*)&As[w * 32 + 16 + lm16][quad];
#pragma unroll
        for (int j = 0; j < 4; j++) bfr[j] = *(const bf16x8*)&Bs[j * 16 + lm16][quad];
#pragma unroll
        for (int i = 0; i < 2; i++)
#pragma unroll
            for (int j = 0; j < 4; j++)
                acc[i][j] = __builtin_amdgcn_mfma_f32_16x16x32_bf16(af[i], bfr[j], acc[i][j], 0, 0, 0);
    }
#pragma unroll
    for (int i = 0; i < 2; i++)
#pragma unroll
        for (int j = 0; j < 4; j++)
#pragma unroll
            for (int r = 0; r < 4; r++) {
                int s = s0 + w * 32 + i * 16 + quad * 4 + r;
                float v = acc[i][j][r] / denomb[(size_t)bh * 4096 + s];
                int e = j * 16 + lm16;
                abf[((size_t)(b * 4096 + s)) * 256 + h * 64 + e] = f2bf(v);
            }
}

// ---------------- pooling tail ----------------
__global__ __launch_bounds__(256) void pool_denom_kernel(
    const float* __restrict__ alpha, float* __restrict__ denomb)
{
    __shared__ float sred[4];
    int b = blockIdx.x, t = threadIdx.x;
    float p = 0.f;
    for (int s = t; s < 4096; s += 256) p += alpha[b * 4096 + s];
    p = wredsum(p);
    if ((t & 63) == 0) sred[t >> 6] = p;
    __syncthreads();
    if (t == 0) denomb[b] = sred[0] + sred[1] + sred[2] + sred[3] + 1e-8f;
}

__global__ __launch_bounds__(256) void pool_out_kernel(
    const float* __restrict__ x, const float* __restrict__ alpha,
    const float* __restrict__ denomb, float* __restrict__ out)
{
    int b = blockIdx.x, chunk = blockIdx.y, t = threadIdx.x;
    float inv = 1.0f / denomb[b];
    float acc = 0.f;
    int s0 = chunk * 128;
    for (int s = s0; s < s0 + 128; s++)
        acc += x[((size_t)(b << 12) + s) * 256 + t] * alpha[(b << 12) + s];
    atomicAdd(&out[b * 256 + t], acc * inv);
}

extern "C" void kernel_launch(void* const* d_in, const int* in_sizes, int n_in,
                              void* d_out, int out_size, void* d_ws, size_t ws_size,
                              hipStream_t stream)
{
    const float* input_embs = (const float*)d_in[0];
    const float* mask  = (const float*)d_in[1];
    const float* pos   = (const float*)d_in[2];
    const float* ln_g  = (const float*)d_in[3];
    const float* ln_b  = (const float*)d_in[4];
    const float* proj  = (const float*)d_in[5];
    const float* Wq = (const float*)d_in[6];  const float* bq = (const float*)d_in[7];
    const float* Wk = (const float*)d_in[8];  const float* bk = (const float*)d_in[9];
    const float* Wv = (const float*)d_in[10]; const float* bv = (const float*)d_in[11];
    const float* Wo = (const float*)d_in[12]; const float* bo = (const float*)d_in[13];
    const float* ln1g = (const float*)d_in[14]; const float* ln1b = (const float*)d_in[15];
    const float* W1 = (const float*)d_in[16]; const float* b1 = (const float*)d_in[17];
    const float* W2 = (const float*)d_in[18]; const float* b2 = (const float*)d_in[19];
    const float* ln2g = (const float*)d_in[20]; const float* ln2b = (const float*)d_in[21];
    const float* p1w = (const float*)d_in[22]; const float* p1b = (const float*)d_in[23];
    const float* p2w = (const float*)d_in[24]; const float* p2b = (const float*)d_in[25];
    float* out = (float*)d_out;
    char* ws = (char*)d_ws;

    size_t off = 0;
    auto alloc = [&](size_t bytes) { size_t o = off; off += WS_ALIGN(bytes); return o; };
    float* xbuf = (float*)(ws + alloc(16384ull * 256 * 4));
    unsigned short* hbf = (unsigned short*)(ws + alloc(16384ull * 256 * 2));   // ln-out / attn-out
    unsigned short* qbf = (unsigned short*)(ws + alloc(16384ull * 256 * 2));
    unsigned short* kbf = (unsigned short*)(ws + alloc(16384ull * 256 * 2));
    unsigned short* vT  = (unsigned short*)(ws + alloc(16384ull * 256 * 2));
    unsigned short* qp  = (unsigned short*)(ws + alloc(16ull * 4096 * 272 * 2)); // alias: FFN mid
    size_t ksum_off = alloc(16ull * 272 * 4);
    float* ksum = (float*)(ws + ksum_off);
    float* ctxT = (float*)(ws + alloc(16ull * 64 * 272 * 4));      // adjacent to ksum (one memset)
    size_t zero_bytes = WS_ALIGN(16ull * 272 * 4) + WS_ALIGN(16ull * 64 * 272 * 4);
    unsigned short* ctxTbf = (unsigned short*)(ws + alloc(16ull * 64 * 272 * 2));
    float* denomb = (float*)(ws + alloc(65536ull * 4));
    float* pmaxb = (float*)(ws + alloc(1024ull * 4));
    float* stabb = (float*)(ws + alloc(256));
    float* alphab = (float*)(ws + alloc(16384ull * 4));
    float* pdenom = (float*)(ws + alloc(256));
    unsigned short* Wqt = (unsigned short*)(ws + alloc(4ull * 65536 * 2));
    unsigned short* Wkt = (unsigned short*)(ws + alloc(4ull * 65536 * 2));
    unsigned short* Wvt = (unsigned short*)(ws + alloc(4ull * 65536 * 2));
    unsigned short* Wot = (unsigned short*)(ws + alloc(4ull * 65536 * 2));
    unsigned short* W1t = (unsigned short*)(ws + alloc(4ull * 262144 * 2));
    unsigned short* W2t = (unsigned short*)(ws + alloc(4ull * 262144 * 2));
    unsigned short* projbf = (unsigned short*)(ws + alloc(4ull * 17024 * 2));
    unsigned short* p1t = (unsigned short*)(ws + alloc(65536ull * 2));
    unsigned short* midbf = qp;   // FFN intermediate aliases qp (disjoint lifetimes)
    unsigned short* abf = hbf;
    // total ~95 MB (< 256 MiB)

    // ---- weight casts (all layers up front) ----
    cast_transpose_kernel<<<dim3(8, 8, 4), 256, 0, stream>>>(Wq, Wqt, 256, 256);
    cast_transpose_kernel<<<dim3(8, 8, 4), 256, 0, stream>>>(Wk, Wkt, 256, 256);
    cast_transpose_kernel<<<dim3(8, 8, 4), 256, 0, stream>>>(Wv, Wvt, 256, 256);
    cast_transpose_kernel<<<dim3(8, 8, 4), 256, 0, stream>>>(Wo, Wot, 256, 256);
    cast_transpose_kernel<<<dim3(32, 8, 4), 256, 0, stream>>>(W1, W1t, 256, 1024);
    cast_transpose_kernel<<<dim3(8, 32, 4), 256, 0, stream>>>(W2, W2t, 1024, 256);
    cast_transpose_kernel<<<dim3(8, 8, 1), 256, 0, stream>>>(p1w, p1t, 256, 256);
    cast_row_kernel<<<67, 256, 0, stream>>>((const float4*)proj, (ushort4*)projbf, 17024);

    // ---- x = LN(input + pos); hbf = LN1_0(x) ----
    add_ln_kernel<false><<<16384, 256, 0, stream>>>(input_embs, pos, ln_g, ln_b, xbuf, nullptr);
    add_ln_kernel<true><<<16384, 256, 0, stream>>>(xbuf, nullptr, ln1g, ln1b, nullptr, hbf);

    for (int i = 0; i < 4; i++) {
        const unsigned short* pj = projbf + (size_t)i * 17024;
        // QKV fused
        qkv_kernel<<<dim3(12, 128), 256, 0, stream>>>(hbf,
            Wqt + (size_t)i * 65536, Wkt + (size_t)i * 65536, Wvt + (size_t)i * 65536,
            bq + i * 256, bk + i * 256, bv + i * 256, qbf, kbf, vT);
        // k stabilizer: dash max (row tiling) -> global reduce
        phi_row_kernel<1><<<dim3(64, 16), 256, 0, stream>>>(kbf, pj, nullptr, nullptr, nullptr, pmaxb);
        reduce_max_kernel<<<1, 256, 0, stream>>>(pmaxb, stabb, 1024);
        // fused k-exp + ksum + ctx
        hipMemsetAsync(ws + ksum_off, 0, zero_bytes, stream);
        ctx_fused_kernel<<<dim3(5, 16, 8), 256, 0, stream>>>(kbf, vT, pj, stabb, ksum, ctxT);
        // q-side fully fused (dash + rowmax + exp + denom)
        phi_row_kernel<0><<<dim3(64, 16), 256, 0, stream>>>(qbf, pj, ksum, qp, denomb, nullptr);
        // attn out
        cast_row_kernel<<<272, 256, 0, stream>>>((const float4*)ctxT, (ushort4*)ctxTbf, 16 * 64 * 272 / 4);
        attn_mfma_kernel<<<dim3(32, 16), 256, 0, stream>>>(qp, ctxTbf, denomb, abf);
        // Wo + residual + LN2 fused
        gemm_fullrow_kernel<0><<<256, 256, 0, stream>>>(abf, Wot + (size_t)i * 65536,
            bo + i * 256, xbuf, ln2g + i * 256, ln2b + i * 256, hbf,
            nullptr, nullptr, nullptr, nullptr, 256);
        // FFN
        ffn1_kernel<<<dim3(16, 128), 256, 0, stream>>>(hbf, W1t + (size_t)i * 262144,
            b1 + i * 1024, midbf, 1024, 256);
        if (i < 3)
            gemm_fullrow_kernel<0><<<256, 256, 0, stream>>>(midbf, W2t + (size_t)i * 262144,
                b2 + i * 256, xbuf, ln1g + (i + 1) * 256, ln1b + (i + 1) * 256, hbf,
                nullptr, nullptr, nullptr, nullptr, 1024);
        else
            gemm_fullrow_kernel<1><<<256, 256, 0, stream>>>(midbf, W2t + (size_t)i * 262144,
                b2 + i * 256, xbuf, nullptr, nullptr, hbf,
                nullptr, nullptr, nullptr, nullptr, 1024);
    }

    // ---- attention pooling (score fused into GEMM) ----
    gemm_fullrow_kernel<2><<<256, 256, 0, stream>>>(hbf, p1t, p1b, nullptr, nullptr, nullptr,
        nullptr, p2w, p2b, mask, alphab, 256);
    pool_denom_kernel<<<4, 256, 0, stream>>>(alphab, pdenom);
    hipMemsetAsync(d_out, 0, (size_t)out_size * sizeof(float), stream);
    pool_out_kernel<<<dim3(4, 32), 256, 0, stream>>>(xbuf, alphab, pdenom, out);
}